// Round 4
// baseline (36374.326 us; speedup 1.0000x reference)
//
#include <hip/hip_runtime.h>
#include <math.h>

typedef short  s16x8 __attribute__((ext_vector_type(8)));
typedef float  f32x4 __attribute__((ext_vector_type(4)));
typedef unsigned short u16;
typedef unsigned long long u64;

#define MFMA16(a, b, c) __builtin_amdgcn_mfma_f32_16x16x32_bf16((a), (b), (c), 0, 0, 0)

#define BB 128
#define SS 512
#define HH 512
#define VV 30
#define TT 64

#define SC_SYS  __HIP_MEMORY_SCOPE_SYSTEM
#define SC_AGT  __HIP_MEMORY_SCOPE_AGENT

__device__ __forceinline__ float b2f(u16 v) {
  union { unsigned int u; float f; } c; c.u = ((unsigned int)v) << 16; return c.f;
}
__device__ __forceinline__ u16 f2b(float f) {
  union { float f; unsigned int u; } c; c.f = f;
  unsigned int r = (c.u + 0x7FFFu + ((c.u >> 16) & 1u)) >> 16;
  return (u16)r;
}
__device__ __forceinline__ float sigm(float x) { return 1.f / (1.f + expf(-x)); }
__device__ __forceinline__ s16x8 ldf(const u16* p) { return *(const s16x8*)p; }

// ---- coherent (sc0|sc1, MALL-level) access helpers: used ONLY for data
// that crosses block boundaries inside a persistent kernel. Relaxed system
// atomics emit no cache-flush instructions (unlike release/acquire fences,
// whose buffer_wbl2/buffer_inv L2 walks were costing ~38us/phase in R3).
__device__ __forceinline__ s16x8 ldv(const u16* p) {   // 16B, 16B-aligned
  union { u64 q[2]; s16x8 v; } u;
  u.q[0] = __hip_atomic_load((const u64*)p,     __ATOMIC_RELAXED, SC_SYS);
  u.q[1] = __hip_atomic_load((const u64*)p + 1, __ATOMIC_RELAXED, SC_SYS);
  return u.v;
}
__device__ __forceinline__ void  st16c(u16* p, u16 v)   { __hip_atomic_store(p, v, __ATOMIC_RELAXED, SC_SYS); }
__device__ __forceinline__ void  stf32c(float* p, float v){ __hip_atomic_store(p, v, __ATOMIC_RELAXED, SC_SYS); }
__device__ __forceinline__ float ldf32c(const float* p) { return __hip_atomic_load(p, __ATOMIC_RELAXED, SC_SYS); }
__device__ __forceinline__ void  sti32c(int* p, int v)  { __hip_atomic_store(p, v, __ATOMIC_RELAXED, SC_SYS); }
__device__ __forceinline__ int   ldi32c(const int* p)   { return __hip_atomic_load(p, __ATOMIC_RELAXED, SC_SYS); }

// ---------------------------------------------------------------------
// Fence-free grid barrier. Correctness: all cross-block data moves via
// sc0|sc1 write-through ops (acked at MALL); __syncthreads() drains each
// wave's vmcnt (compiler emits s_waitcnt vmcnt(0) before s_barrier), so
// by the time thread0 increments the MALL-resident counter, this block's
// published data is MALL-visible. Consumers spin on the counter and then
// read with sc0|sc1 loads (always served at MALL) -> no invalidate needed.
// Monotone counter; timeout (~5ms) turns a pathological hang into a
// terminating wrong-answer run instead of a dead container.
// ---------------------------------------------------------------------
__device__ unsigned int g_bar[2];

__device__ __forceinline__ void gridbar(unsigned int* cnt, unsigned int target) {
  __syncthreads();
  if (threadIdx.x == 0) {
    asm volatile("s_waitcnt vmcnt(0) lgkmcnt(0)" ::: "memory");
    __hip_atomic_fetch_add(cnt, 1u, __ATOMIC_RELAXED, SC_AGT);
    unsigned long long t0 = __builtin_amdgcn_s_memrealtime();
    while (__hip_atomic_load(cnt, __ATOMIC_RELAXED, SC_AGT) < target) {
      __builtin_amdgcn_s_sleep(2);
      if (__builtin_amdgcn_s_memrealtime() - t0 > (1ull << 19)) break;
    }
  }
  __syncthreads();
}

// Split-f32 format: per logical row of K=512, u16 row of 1024: [hi x512 | lo x512].
// hi = bf16(v), lo = bf16(v - hi). GEMM does hi*hi + hi*lo + lo*hi (Markidis).

// =====================================================================
// Dual-input GRU cell (layer-1 / decoder): 64 block-roles x 256 thr.
// coh_a1/coh_a2: A operand buffers are cross-block (use MALL loads).
// coh_h: hf state is read by other blocks (sim/attn) -> MALL RMW.
// =====================================================================
__device__ __forceinline__ void gru_dual(
    int bx, bool coh_a1, bool coh_a2, bool coh_h,
    const u16* __restrict__ A1s, const int* __restrict__ gather,
    const u16* __restrict__ A2s,
    const u16* __restrict__ Wihs, const u16* __restrict__ Whhs,
    const float* __restrict__ bih, const float* __restrict__ bhh,
    float* __restrict__ hf, u16* __restrict__ hs_new,
    u16* __restrict__ oe, size_t oe_mstride)
{
  const int tid  = threadIdx.x;
  const int wave = tid >> 6, lane = tid & 63;
  const int lrow = lane & 15, lq = lane >> 4;
  const int j0 = (bx >> 1) * 16;
  const int m0 = (bx & 1) * 64 + wave * 16;

  const u16* a1p;
  if (gather) a1p = A1s + (size_t)ldi32c(&gather[m0 + lrow]) * 1024 + lq * 8;
  else        a1p = A1s + (size_t)(m0 + lrow) * 1024 + lq * 8;
  const u16* a2p = A2s + (size_t)(m0 + lrow) * 1024 + lq * 8;

  const u16* bp[6];
#pragma unroll
  for (int t = 0; t < 6; ++t) {
    int g = (t < 3) ? t : t - 3;
    const u16* W = (t < 3) ? Wihs : Whhs;
    bp[t] = W + (size_t)(g * HH + j0 + lrow) * 1024 + lq * 8;
  }

  f32x4 acc[6];
#pragma unroll
  for (int t = 0; t < 6; ++t) acc[t] = (f32x4){0.f, 0.f, 0.f, 0.f};

  for (int ks = 0; ks < HH; ks += 32) {
    s16x8 a1h = coh_a1 ? ldv(a1p) : ldf(a1p);
    s16x8 a1l = coh_a1 ? ldv(a1p + 512) : ldf(a1p + 512); a1p += 32;
    s16x8 a2h = coh_a2 ? ldv(a2p) : ldf(a2p);
    s16x8 a2l = coh_a2 ? ldv(a2p + 512) : ldf(a2p + 512); a2p += 32;
#pragma unroll
    for (int t = 0; t < 6; ++t) {
      s16x8 bh = ldf(bp[t]), bl = ldf(bp[t] + 512); bp[t] += 32;
      s16x8 ah = (t < 3) ? a1h : a2h;
      s16x8 al = (t < 3) ? a1l : a2l;
      acc[t] = MFMA16(ah, bh, acc[t]);
      acc[t] = MFMA16(ah, bl, acc[t]);
      acc[t] = MFMA16(al, bh, acc[t]);
    }
  }

  const int c = j0 + lrow;
  const float bir = bih[c], biz = bih[HH + c], bin = bih[2 * HH + c];
  const float bhr = bhh[c], bhz = bhh[HH + c], bhn = bhh[2 * HH + c];
#pragma unroll
  for (int r = 0; r < 4; ++r) {
    int m = m0 + lq * 4 + r;
    float ir = acc[0][r] + bir, iz = acc[1][r] + biz, inn = acc[2][r] + bin;
    float hr = acc[3][r] + bhr, hz = acc[4][r] + bhz, hn = acc[5][r] + bhn;
    float rr = sigm(ir + hr);
    float zz = sigm(iz + hz);
    float nn = tanhf(inn + rr * hn);
    float hp = coh_h ? ldf32c(&hf[(size_t)m * HH + c]) : hf[(size_t)m * HH + c];
    float hv = (1.f - zz) * nn + zz * hp;
    if (coh_h) stf32c(&hf[(size_t)m * HH + c], hv);
    else       hf[(size_t)m * HH + c] = hv;
    u16 hi = f2b(hv);
    st16c(&hs_new[(size_t)m * 1024 + c], hi);
    st16c(&hs_new[(size_t)m * 1024 + 512 + c], f2b(hv - b2f(hi)));
    if (oe) oe[(size_t)m * oe_mstride + c] = hi;   // read only by next kernel
  }
}

// Encoder layer-0: gh via MFMA (split A, split Whh0); gi inline f32 (K=2, exact).
// 32 block-roles x 256 thr; wave covers 32 m-rows (2 m-tiles).
__device__ __forceinline__ void gru_l0(
    int bx, int p,
    const float* __restrict__ x, const float* __restrict__ Wih0,
    const u16* __restrict__ Whh0s,
    const float* __restrict__ bih0, const float* __restrict__ bhh0,
    const u16* __restrict__ As,
    float* __restrict__ af, u16* __restrict__ as_new)
{
  const int tid  = threadIdx.x;
  const int wave = tid >> 6, lane = tid & 63;
  const int lrow = lane & 15, lq = lane >> 4;
  const int j0 = bx * 16;
  const int mw = wave * 32;

  const u16* ap0 = As + (size_t)(mw + lrow) * 1024 + lq * 8;
  const u16* ap1 = As + (size_t)(mw + 16 + lrow) * 1024 + lq * 8;
  const u16* bp[3];
#pragma unroll
  for (int t = 0; t < 3; ++t)
    bp[t] = Whh0s + (size_t)(t * HH + j0 + lrow) * 1024 + lq * 8;

  f32x4 acc[2][3];
#pragma unroll
  for (int i = 0; i < 2; ++i)
#pragma unroll
    for (int t = 0; t < 3; ++t) acc[i][t] = (f32x4){0.f, 0.f, 0.f, 0.f};

  for (int ks = 0; ks < HH; ks += 32) {
    s16x8 a0h = ldv(ap0), a0l = ldv(ap0 + 512); ap0 += 32;
    s16x8 a1h = ldv(ap1), a1l = ldv(ap1 + 512); ap1 += 32;
#pragma unroll
    for (int t = 0; t < 3; ++t) {
      s16x8 bh = ldf(bp[t]), bl = ldf(bp[t] + 512); bp[t] += 32;
      acc[0][t] = MFMA16(a0h, bh, acc[0][t]);
      acc[0][t] = MFMA16(a0h, bl, acc[0][t]);
      acc[0][t] = MFMA16(a0l, bh, acc[0][t]);
      acc[1][t] = MFMA16(a1h, bh, acc[1][t]);
      acc[1][t] = MFMA16(a1h, bl, acc[1][t]);
      acc[1][t] = MFMA16(a1l, bh, acc[1][t]);
    }
  }

  const int c = j0 + lrow;
  const float bir = bih0[c], biz = bih0[HH + c], bin = bih0[2 * HH + c];
  const float bhr = bhh0[c], bhz = bhh0[HH + c], bhn = bhh0[2 * HH + c];
  const float wr0 = Wih0[(size_t)c * 2],            wr1 = Wih0[(size_t)c * 2 + 1];
  const float wz0 = Wih0[(size_t)(HH + c) * 2],     wz1 = Wih0[(size_t)(HH + c) * 2 + 1];
  const float wn0 = Wih0[(size_t)(2 * HH + c) * 2], wn1 = Wih0[(size_t)(2 * HH + c) * 2 + 1];
#pragma unroll
  for (int tm = 0; tm < 2; ++tm) {
#pragma unroll
    for (int r = 0; r < 4; ++r) {
      int m = mw + tm * 16 + lq * 4 + r;
      float x0 = x[((size_t)m * SS + p) * 2];
      float x1 = x[((size_t)m * SS + p) * 2 + 1];
      float ir  = bir + x0 * wr0 + x1 * wr1;
      float iz  = biz + x0 * wz0 + x1 * wz1;
      float inn = bin + x0 * wn0 + x1 * wn1;
      float hr = acc[tm][0][r] + bhr, hz = acc[tm][1][r] + bhz, hn = acc[tm][2][r] + bhn;
      float rr = sigm(ir + hr);
      float zz = sigm(iz + hz);
      float nn = tanhf(inn + rr * hn);
      float hp = af[(size_t)m * HH + c];      // same-thread RMW
      float hv = (1.f - zz) * nn + zz * hp;
      af[(size_t)m * HH + c] = hv;
      u16 hi = f2b(hv);
      st16c(&as_new[(size_t)m * 1024 + c], hi);
      st16c(&as_new[(size_t)m * 1024 + 512 + c], f2b(hv - b2f(hi)));
    }
  }
}

// sim[s][b] = dot(out_enc[b,s,:], n1[b,:]). 256 block-roles: b=bx>>1,
// s-half=bx&1; wave covers 64 s-rows. n1f is cross-block -> MALL loads;
// oe is read-only -> normal cached loads; simt -> MALL stores.
__device__ __forceinline__ void sim_block(
    int bx, const float* __restrict__ n1f, const u16* __restrict__ oe,
    float* __restrict__ simt)
{
  const int b = bx >> 1, sc = bx & 1;
  const int wave = threadIdx.x >> 6, lane = threadIdx.x & 63;
  float xr[8];
  const float* xp = n1f + (size_t)b * HH + lane * 8;
#pragma unroll
  for (int j = 0; j < 8; ++j) xr[j] = ldf32c(xp + j);
  int s0 = sc * 256 + wave * 64;
  for (int i = 0; i < 64; ++i) {
    int s = s0 + i;
    s16x8 ov = *(const s16x8*)(oe + ((size_t)b * SS + s) * HH + lane * 8);
    float acc = 0.f;
#pragma unroll
    for (int j = 0; j < 8; ++j) acc += xr[j] * b2f((u16)ov[j]);
    for (int off = 32; off; off >>= 1) acc += __shfl_down(acc, off);
    if (lane == 0) stf32c(&simt[(size_t)s * BB + b], acc);
  }
}

// Fused: softmax over BATCH (reference dim=0 quirk) -> attention -> logits ->
// argmax feedback. One block-role per batch element.
__device__ __forceinline__ void attn_block(
    int b, int tstep, const float* __restrict__ simt, const float* __restrict__ n1f,
    const u16* __restrict__ oe, const float* __restrict__ fcW,
    const float* __restrict__ fcb, float* __restrict__ dout,
    int* __restrict__ tok)
{
  __shared__ float wsm[SS];
  __shared__ float xv[2 * HH];
  __shared__ float lg[32];
  const int t = threadIdx.x;

  for (int s = t; s < SS; s += 256) {
    const float* row = simt + (size_t)s * BB;
    float mx = -1e30f;
    for (int i = 0; i < BB; ++i) mx = fmaxf(mx, ldf32c(&row[i]));
    float e = 0.f;
    for (int i = 0; i < BB; ++i) e += expf(ldf32c(&row[i]) - mx);
    wsm[s] = expf(ldf32c(&row[b]) - mx) / e;
  }
  xv[t]       = ldf32c(&n1f[(size_t)b * HH + t]);
  xv[t + 256] = ldf32c(&n1f[(size_t)b * HH + t + 256]);
  __syncthreads();

  {
    float a0 = 0.f, a1 = 0.f;
    const u16* base = oe + (size_t)b * SS * HH;   // read-only: cached loads
    for (int s = 0; s < SS; ++s) {
      float w = wsm[s];
      a0 += w * b2f(base[(size_t)s * HH + t]);
      a1 += w * b2f(base[(size_t)s * HH + t + 256]);
    }
    xv[HH + t]       = a0;
    xv[HH + t + 256] = a1;
  }
  __syncthreads();

  int wave = t >> 6, lane = t & 63;
  for (int v = wave; v < VV; v += 4) {
    const float* wr = fcW + (size_t)v * (2 * HH);
    float acc = 0.f;
#pragma unroll
    for (int i = 0; i < 16; ++i) acc += xv[i * 64 + lane] * wr[i * 64 + lane];
    for (int off = 32; off; off >>= 1) acc += __shfl_down(acc, off);
    if (lane == 0) {
      float lv = acc + fcb[v];
      lg[v] = lv;
      dout[(size_t)b * (TT * VV) + (size_t)tstep * VV + v] = lv;  // host-read only
    }
  }
  __syncthreads();

  if (t == 0) {
    float best = lg[0]; int bi = 0;
    for (int v = 1; v < VV; ++v) if (lg[v] > best) { best = lg[v]; bi = v; }
    sti32c(&tok[b], bi);
  }
}

// =====================================================================
// Persistent encoder: 96 blocks (<=256 CUs -> co-resident), 513 phases.
// Phase p: blocks 0..31 = layer0@t=p (p<S); 32..95 = layer1@t=p-1 (p>0).
// =====================================================================
__global__ __launch_bounds__(256) void enc_persist(
    const float* __restrict__ x, const float* __restrict__ Wih0,
    const u16* __restrict__ Whh0s,
    const float* __restrict__ bih0, const float* __restrict__ bhh0,
    const u16* __restrict__ Wih1s, const u16* __restrict__ Whh1s,
    const float* __restrict__ bih1, const float* __restrict__ bhh1,
    u16* ABF0, u16* ABF1, float* af,
    u16* CBF0, u16* CBF1, float* cf,
    u16* out_enc)
{
  const int bx = blockIdx.x;
  const u16* pa = ABF0; u16* pa_n = ABF1;
  const u16* pc = CBF0; u16* pc_n = CBF1;
  for (int p = 0; p <= SS; ++p) {
    if (bx < 32) {
      if (p < SS) gru_l0(bx, p, x, Wih0, Whh0s, bih0, bhh0, pa, af, pa_n);
    } else {
      if (p > 0) {
        u16* oe = out_enc + (size_t)(p - 1) * HH;
        gru_dual(bx - 32, true, true, false,
                 pa, nullptr, pc, Wih1s, Whh1s, bih1, bhh1,
                 cf, pc_n, oe, (size_t)SS * HH);
      }
    }
    gridbar(&g_bar[0], 96u * (unsigned)(p + 1));
    const u16* tp;
    tp = pa; pa = pa_n; pa_n = (u16*)tp;
    tp = pc; pc = pc_n; pc_n = (u16*)tp;
  }
}

// =====================================================================
// Persistent decoder: 256 blocks (1/CU -> co-resident), 64 steps x 4 bars.
// =====================================================================
__global__ __launch_bounds__(256) void dec_persist(
    const u16* __restrict__ EMBs, int* tok,
    const u16* __restrict__ WdIH0, const u16* __restrict__ WdHH0,
    const float* __restrict__ dbih0, const float* __restrict__ dbhh0,
    const u16* __restrict__ WdIH1, const u16* __restrict__ WdHH1,
    const float* __restrict__ dbih1, const float* __restrict__ dbhh1,
    float* af, float* cf,
    u16* D0A, u16* D0B, u16* D1A, u16* D1B,
    const u16* __restrict__ oe, float* simt,
    const float* __restrict__ fcW, const float* __restrict__ fcb,
    float* dout)
{
  const int bx = blockIdx.x;
  const u16* d0c = D0A; u16* d0n = D0B;
  const u16* d1c = D1A; u16* d1n = D1B;
  unsigned int nb = 0;
  for (int t = 0; t < TT; ++t) {
    if (bx < 64)
      gru_dual(bx, false, true, false,
               EMBs, tok, d0c, WdIH0, WdHH0, dbih0, dbhh0, af, d0n,
               nullptr, 0);
    gridbar(&g_bar[1], 256u * (++nb));
    { const u16* tp = d0c; d0c = d0n; d0n = (u16*)tp; }

    if (bx < 64)
      gru_dual(bx, true, true, true,
               d0c, nullptr, d1c, WdIH1, WdHH1, dbih1, dbhh1, cf, d1n,
               nullptr, 0);
    gridbar(&g_bar[1], 256u * (++nb));
    { const u16* tp = d1c; d1c = d1n; d1n = (u16*)tp; }

    sim_block(bx, cf, oe, simt);
    gridbar(&g_bar[1], 256u * (++nb));

    if (bx < BB) attn_block(bx, t, simt, cf, oe, fcW, fcb, dout, tok);
    gridbar(&g_bar[1], 256u * (++nb));
  }
}

// Split all 7 weight matrices + embedding in one launch.
__global__ __launch_bounds__(256) void splitall(
    const float* __restrict__ s0, u16* d0, const float* __restrict__ s1, u16* d1,
    const float* __restrict__ s2, u16* d2, const float* __restrict__ s3, u16* d3,
    const float* __restrict__ s4, u16* d4, const float* __restrict__ s5, u16* d5,
    const float* __restrict__ s6, u16* d6, const float* __restrict__ s7, u16* d7)
{
  const int WN = 3 * HH * HH;  // 786432
  int i = blockIdx.x * 256 + threadIdx.x;
  const float* s; u16* d; int j;
  if      (i < 1 * WN) { s = s0; d = d0; j = i; }
  else if (i < 2 * WN) { s = s1; d = d1; j = i - 1 * WN; }
  else if (i < 3 * WN) { s = s2; d = d2; j = i - 2 * WN; }
  else if (i < 4 * WN) { s = s3; d = d3; j = i - 3 * WN; }
  else if (i < 5 * WN) { s = s4; d = d4; j = i - 4 * WN; }
  else if (i < 6 * WN) { s = s5; d = d5; j = i - 5 * WN; }
  else if (i < 7 * WN) { s = s6; d = d6; j = i - 6 * WN; }
  else { j = i - 7 * WN; if (j >= VV * HH) return; s = s7; d = d7; }
  int r = j >> 9, k = j & 511;
  float v = s[j];
  u16 hi = f2b(v);
  d[(size_t)r * 1024 + k]       = hi;
  d[(size_t)r * 1024 + 512 + k] = f2b(v - b2f(hi));
}

__global__ __launch_bounds__(256) void initk(
    float* af, float* cf, u16* b0, u16* b1, u16* b2, u16* b3, int* tok)
{
  int i = blockIdx.x * 256 + threadIdx.x;   // 131072 threads
  b0[i] = 0; b1[i] = 0; b2[i] = 0; b3[i] = 0;
  if (i < BB * HH) { af[i] = 0.f; cf[i] = 0.f; }
  if (i < BB) tok[i] = 0;
  if (i < 2) g_bar[i] = 0;
}

__global__ __launch_bounds__(256) void finalize(
    const float* __restrict__ d0, const float* __restrict__ d1,
    float* __restrict__ oh)
{
  int i = blockIdx.x * 256 + threadIdx.x;
  oh[i]           = d0[i];
  oh[BB * HH + i] = d1[i];
}

extern "C" void kernel_launch(void* const* d_in, const int* in_sizes, int n_in,
                              void* d_out, int out_size, void* d_ws, size_t ws_size,
                              hipStream_t stream) {
  const float* x     = (const float*)d_in[0];
  const float* emb   = (const float*)d_in[1];
  const float* eWih0 = (const float*)d_in[2];
  const float* eWhh0 = (const float*)d_in[3];
  const float* ebih0 = (const float*)d_in[4];
  const float* ebhh0 = (const float*)d_in[5];
  const float* eWih1 = (const float*)d_in[6];
  const float* eWhh1 = (const float*)d_in[7];
  const float* ebih1 = (const float*)d_in[8];
  const float* ebhh1 = (const float*)d_in[9];
  const float* dWih0 = (const float*)d_in[10];
  const float* dWhh0 = (const float*)d_in[11];
  const float* dbih0 = (const float*)d_in[12];
  const float* dbhh0 = (const float*)d_in[13];
  const float* dWih1 = (const float*)d_in[14];
  const float* dWhh1 = (const float*)d_in[15];
  const float* dbih1 = (const float*)d_in[16];
  const float* dbhh1 = (const float*)d_in[17];
  const float* fcW   = (const float*)d_in[18];
  const float* fcb   = (const float*)d_in[19];
  float* dout = (float*)d_out;

  char* wsb = (char*)d_ws;
  float* af   = (float*)(wsb + 0);          // 128x512 f32 (a / d0 state, RMW)
  float* cf   = (float*)(wsb + 262144);     // 128x512 f32 (c / d1 state, RMW)
  u16* ABF0   = (u16*)(wsb + 524288);       // split states 128x1024 u16 each
  u16* ABF1   = (u16*)(wsb + 786432);
  u16* CBF0   = (u16*)(wsb + 1048576);
  u16* CBF1   = (u16*)(wsb + 1310720);
  int* tok    = (int*)(wsb + 1572864);
  float* simt = (float*)(wsb + 1573376);    // [S][B] f32, 256 KB
  u16* WeHH0  = (u16*)(wsb + 1835520);      // split weights, 3 MB each
  u16* WeIH1  = (u16*)(wsb + 4981248);
  u16* WeHH1  = (u16*)(wsb + 8126976);
  u16* WdIH0  = (u16*)(wsb + 11272704);
  u16* WdHH0  = (u16*)(wsb + 14418432);
  u16* WdIH1  = (u16*)(wsb + 17564160);
  u16* WdHH1  = (u16*)(wsb + 20709888);
  u16* EMBs   = (u16*)(wsb + 23855616);     // 30x1024 u16
  u16* oe     = (u16*)(wsb + 23917056);     // out_enc bf16 [B][S][H], 64 MiB

  initk<<<512, 256, 0, stream>>>(af, cf, ABF0, ABF1, CBF0, CBF1, tok);

  splitall<<<21564, 256, 0, stream>>>(eWhh0, WeHH0, eWih1, WeIH1, eWhh1, WeHH1,
                                      dWih0, WdIH0, dWhh0, WdHH0, dWih1, WdIH1,
                                      dWhh1, WdHH1, emb, EMBs);

  enc_persist<<<96, 256, 0, stream>>>(x, eWih0, WeHH0, ebih0, ebhh0,
                                      WeIH1, WeHH1, ebih1, ebhh1,
                                      ABF0, ABF1, af, CBF0, CBF1, cf, oe);

  // a_511 split in ABF0 (written p=511); c_511 split in CBF1 (written p=512)
  dec_persist<<<256, 256, 0, stream>>>(EMBs, tok, WdIH0, WdHH0, dbih0, dbhh0,
                                       WdIH1, WdHH1, dbih1, dbhh1,
                                       af, cf, ABF0, ABF1, CBF1, CBF0,
                                       oe, simt, fcW, fcb, dout);

  finalize<<<256, 256, 0, stream>>>(af, cf, dout + (size_t)BB * TT * VV);
}

// Round 6
// 33959.021 us; speedup vs baseline: 1.0711x; 1.0711x over previous
//
#include <hip/hip_runtime.h>
#include <math.h>

typedef short  s16x8 __attribute__((ext_vector_type(8)));
typedef float  f32x4 __attribute__((ext_vector_type(4)));
typedef unsigned short u16;
typedef unsigned long long u64;

#define MFMA16(a, b, c) __builtin_amdgcn_mfma_f32_16x16x32_bf16((a), (b), (c), 0, 0, 0)

#define BB 128
#define SS 512
#define HH 512
#define VV 30
#define TT 64

#define SC_SYS  __HIP_MEMORY_SCOPE_SYSTEM
#define SC_AGT  __HIP_MEMORY_SCOPE_AGENT

__device__ __forceinline__ float b2f(u16 v) {
  union { unsigned int u; float f; } c; c.u = ((unsigned int)v) << 16; return c.f;
}
__device__ __forceinline__ u16 f2b(float f) {
  union { float f; unsigned int u; } c; c.f = f;
  unsigned int r = (c.u + 0x7FFFu + ((c.u >> 16) & 1u)) >> 16;
  return (u16)r;
}
__device__ __forceinline__ float sigm(float x) { return 1.f / (1.f + expf(-x)); }
__device__ __forceinline__ s16x8 ldf(const u16* p) { return *(const s16x8*)p; }

// ---- coherent (MALL-level) helpers: ONLY for data crossing block
// boundaries inside a persistent kernel. Relaxed -> no L2 wb/inv walks.
__device__ __forceinline__ u64  ld64c(const u64* p)      { return __hip_atomic_load(p, __ATOMIC_RELAXED, SC_SYS); }
__device__ __forceinline__ void st16c(u16* p, u16 v)     { __hip_atomic_store(p, v, __ATOMIC_RELAXED, SC_SYS); }
__device__ __forceinline__ void stf32c(float* p, float v){ __hip_atomic_store(p, v, __ATOMIC_RELAXED, SC_SYS); }
__device__ __forceinline__ float ldf32c(const float* p)  { return __hip_atomic_load(p, __ATOMIC_RELAXED, SC_SYS); }
__device__ __forceinline__ void sti32c(int* p, int v)    { __hip_atomic_store(p, v, __ATOMIC_RELAXED, SC_SYS); }
__device__ __forceinline__ int  ldi32c(const int* p)     { return __hip_atomic_load(p, __ATOMIC_RELAXED, SC_SYS); }

// ---------------------------------------------------------------------
// Dataflow synchronization: per-producer-group monotone counters.
// arrive(): non-returning atomicAdd (fire-and-forget, agent scope).
// waitp(): relaxed poll + timeout (pathological hang -> terminating run).
// Visibility: producers publish via MALL (sc) stores; each wave's stores
// are vmcnt-drained by the __syncthreads inside arrive().
// ---------------------------------------------------------------------
__device__ unsigned int g_cnt[8];
__device__ float g_smx[SS], g_ssum[SS];

#define C_L0 0
#define C_L1 1
#define C_G0 2
#define C_G1 3
#define C_SIM 4
#define C_SMX 5
#define C_ATT 6

__device__ __forceinline__ void waitp(int idx, int target) {
  if (target <= 0) return;
  unsigned long long t0 = __builtin_amdgcn_s_memrealtime();
  while ((int)__hip_atomic_load(&g_cnt[idx], __ATOMIC_RELAXED, SC_AGT) < target) {
    __builtin_amdgcn_s_sleep(1);
    if (__builtin_amdgcn_s_memrealtime() - t0 > (1ull << 21)) break;
  }
}
__device__ __forceinline__ void waitc2(int i1, int t1, int i2, int t2) {
  if (threadIdx.x == 0) { waitp(i1, t1); waitp(i2, t2); }
  __syncthreads();
}
__device__ __forceinline__ void waitc3(int i1, int t1, int i2, int t2, int i3, int t3) {
  if (threadIdx.x == 0) { waitp(i1, t1); waitp(i2, t2); waitp(i3, t3); }
  __syncthreads();
}
__device__ __forceinline__ void waitc4(int i1, int t1, int i2, int t2, int i3, int t3, int i4, int t4) {
  if (threadIdx.x == 0) { waitp(i1, t1); waitp(i2, t2); waitp(i3, t3); waitp(i4, t4); }
  __syncthreads();
}
__device__ __forceinline__ void arrive(int idx) {
  __syncthreads();
  if (threadIdx.x == 0) {
    asm volatile("s_waitcnt vmcnt(0) lgkmcnt(0)" ::: "memory");
    atomicAdd(&g_cnt[idx], 1u);
  }
}

// ---------------------------------------------------------------------
// LDS staging of split-format state (rows x [hi128|lo128] u16 K-chunks).
// Row r = 512B = 32 slots of 16B; slot s stored at (s ^ (r&7)) -> XOR
// swizzle kills the stride-512B ds_read_b128 bank conflict. Bulk ld64c
// batches amortize MALL latency. Each row needs 128 u16 hi + 128 lo:
// 2 threads/row -> 16 u64 per half per thread (R5 bug: had 8 = half).
// ---------------------------------------------------------------------
__device__ __forceinline__ s16x8 ldl(const u16* SM, int row, int slot) {
  return *(const s16x8*)&SM[(row << 8) + ((slot ^ (row & 7)) << 3)];
}

// 2 sources x 64 rows (enc-l1 / dec-gru1): src = tid>>7, r = (tid>>1)&63, h = tid&1
__device__ __forceinline__ void stage64_2(u16* SM, const u16* A1, const u16* A2,
                                          int mbase, int ks0) {
  const int t = threadIdx.x;
  const int src = t >> 7, r = (t >> 1) & 63, h = t & 1;
  const u16* gp = (src ? A2 : A1) + (size_t)(mbase + r) * 1024 + ks0 + h * 64;
  u64 th_[16], tl_[16];
#pragma unroll
  for (int j = 0; j < 16; ++j) th_[j] = ld64c((const u64*)gp + j);
#pragma unroll
  for (int j = 0; j < 16; ++j) tl_[j] = ld64c((const u64*)(gp + 512) + j);
  u16* Lb = SM + ((src * 64 + r) << 8);
  const int rx = r & 7;
#pragma unroll
  for (int j = 0; j < 16; ++j) {
    const int sl = h * 8 + (j >> 1);
    *(u64*)&Lb[((sl ^ rx) << 3) + ((j & 1) << 2)]        = th_[j];
    *(u64*)&Lb[(((16 + sl) ^ rx) << 3) + ((j & 1) << 2)] = tl_[j];
  }
}

// 1 source x 64 rows into rows 64..127 (dec-gru0 a2): r = (tid>>2)&63, q = tid&3
__device__ __forceinline__ void stage64_1(u16* SM, const u16* A2, int mbase, int ks0) {
  const int t = threadIdx.x;
  const int r = (t >> 2) & 63, q = t & 3;
  const u16* gp = A2 + (size_t)(mbase + r) * 1024 + ks0 + q * 32;
  u64 th_[8], tl_[8];
#pragma unroll
  for (int j = 0; j < 8; ++j) th_[j] = ld64c((const u64*)gp + j);
#pragma unroll
  for (int j = 0; j < 8; ++j) tl_[j] = ld64c((const u64*)(gp + 512) + j);
  u16* Lb = SM + ((64 + r) << 8);
  const int rx = r & 7;
#pragma unroll
  for (int j = 0; j < 8; ++j) {
    const int sl = q * 4 + (j >> 1);
    *(u64*)&Lb[((sl ^ rx) << 3) + ((j & 1) << 2)]        = th_[j];
    *(u64*)&Lb[(((16 + sl) ^ rx) << 3) + ((j & 1) << 2)] = tl_[j];
  }
}

// 1 source x 128 rows (enc-l0): r = tid>>1, h = tid&1
__device__ __forceinline__ void stage128(u16* SM, const u16* As, int ks0) {
  const int t = threadIdx.x;
  const int r = t >> 1, h = t & 1;
  const u16* gp = As + (size_t)r * 1024 + ks0 + h * 64;
  u64 th_[16], tl_[16];
#pragma unroll
  for (int j = 0; j < 16; ++j) th_[j] = ld64c((const u64*)gp + j);
#pragma unroll
  for (int j = 0; j < 16; ++j) tl_[j] = ld64c((const u64*)(gp + 512) + j);
  u16* Lb = SM + (r << 8);
  const int rx = r & 7;
#pragma unroll
  for (int j = 0; j < 16; ++j) {
    const int sl = h * 8 + (j >> 1);
    *(u64*)&Lb[((sl ^ rx) << 3) + ((j & 1) << 2)]        = th_[j];
    *(u64*)&Lb[(((16 + sl) ^ rx) << 3) + ((j & 1) << 2)] = tl_[j];
  }
}

// Split-f32 format: per logical row of K=512, u16 row of 1024: [hi x512 | lo x512].
// hi = bf16(v), lo = bf16(v - hi). GEMM does hi*hi + hi*lo + lo*hi (Markidis).

// =====================================================================
// Dual-input GRU cell (enc-l1 / decoder): 64 block-roles x 256 thr.
// GATHER: a1 = EMBs[gather[m]] via plain cached loads (read-only);
// otherwise a1 staged. a2 always staged. Weights plain cached (L2-warm).
// =====================================================================
template <bool GATHER, bool COH_H>
__device__ __forceinline__ void gru_dual_staged(
    int bx, u16* SM,
    const u16* __restrict__ A1s, const int* __restrict__ gather,
    const u16* __restrict__ A2s,
    const u16* __restrict__ Wihs, const u16* __restrict__ Whhs,
    const float* __restrict__ bih, const float* __restrict__ bhh,
    float* __restrict__ hf, u16* __restrict__ hs_new,
    u16* __restrict__ oe, size_t oe_mstride)
{
  const int tid  = threadIdx.x;
  const int wave = tid >> 6, lane = tid & 63;
  const int lrow = lane & 15, lq = lane >> 4;
  const int j0 = (bx >> 1) * 16;
  const int mbase = (bx & 1) * 64;
  const int lr = wave * 16 + lrow;       // local row 0..63
  const int m0 = mbase + wave * 16;

  const u16* a1p = nullptr;
  if (GATHER)
    a1p = A1s + (size_t)ldi32c(&gather[m0 + lrow]) * 1024 + lq * 8;

  const u16* bp[6];
#pragma unroll
  for (int t = 0; t < 6; ++t) {
    int g = (t < 3) ? t : t - 3;
    const u16* W = (t < 3) ? Wihs : Whhs;
    bp[t] = W + (size_t)(g * HH + j0 + lrow) * 1024 + lq * 8;
  }

  f32x4 acc[6];
#pragma unroll
  for (int t = 0; t < 6; ++t) acc[t] = (f32x4){0.f, 0.f, 0.f, 0.f};

  for (int kc = 0; kc < 4; ++kc) {
    const int ks0 = kc * 128;
    if (GATHER) stage64_1(SM, A2s, mbase, ks0);
    else        stage64_2(SM, A1s, A2s, mbase, ks0);
    __syncthreads();
#pragma unroll
    for (int ki = 0; ki < 4; ++ki) {
      const int sl = ki * 4 + lq;
      s16x8 a1h, a1l;
      if (GATHER) { a1h = ldf(a1p); a1l = ldf(a1p + 512); a1p += 32; }
      else        { a1h = ldl(SM, lr, sl); a1l = ldl(SM, lr, 16 + sl); }
      s16x8 a2h = ldl(SM, 64 + lr, sl), a2l = ldl(SM, 64 + lr, 16 + sl);
#pragma unroll
      for (int t = 0; t < 6; ++t) {
        s16x8 bh = ldf(bp[t]), bl = ldf(bp[t] + 512); bp[t] += 32;
        s16x8 ah = (t < 3) ? a1h : a2h;
        s16x8 al = (t < 3) ? a1l : a2l;
        acc[t] = MFMA16(ah, bh, acc[t]);
        acc[t] = MFMA16(ah, bl, acc[t]);
        acc[t] = MFMA16(al, bh, acc[t]);
      }
    }
    __syncthreads();
  }

  const int c = j0 + lrow;
  const float bir = bih[c], biz = bih[HH + c], bin = bih[2 * HH + c];
  const float bhr = bhh[c], bhz = bhh[HH + c], bhn = bhh[2 * HH + c];
#pragma unroll
  for (int r = 0; r < 4; ++r) {
    int m = mbase + wave * 16 + lq * 4 + r;
    float ir = acc[0][r] + bir, iz = acc[1][r] + biz, inn = acc[2][r] + bin;
    float hr = acc[3][r] + bhr, hz = acc[4][r] + bhz, hn = acc[5][r] + bhn;
    float rr = sigm(ir + hr);
    float zz = sigm(iz + hz);
    float nn = tanhf(inn + rr * hn);
    float hp = COH_H ? ldf32c(&hf[(size_t)m * HH + c]) : hf[(size_t)m * HH + c];
    float hv = (1.f - zz) * nn + zz * hp;
    if (COH_H) stf32c(&hf[(size_t)m * HH + c], hv);
    else       hf[(size_t)m * HH + c] = hv;
    u16 hi = f2b(hv);
    st16c(&hs_new[(size_t)m * 1024 + c], hi);
    st16c(&hs_new[(size_t)m * 1024 + 512 + c], f2b(hv - b2f(hi)));
    if (oe) oe[(size_t)m * oe_mstride + c] = hi;   // read only by next kernel
  }
}

// Encoder layer-0: gh via MFMA (staged split A, cached split Whh0); gi inline f32.
__device__ __forceinline__ void gru_l0_staged(
    int bx, int p, u16* SM,
    const float* __restrict__ x, const float* __restrict__ Wih0,
    const u16* __restrict__ Whh0s,
    const float* __restrict__ bih0, const float* __restrict__ bhh0,
    const u16* __restrict__ As,
    float* __restrict__ af, u16* __restrict__ as_new)
{
  const int tid  = threadIdx.x;
  const int wave = tid >> 6, lane = tid & 63;
  const int lrow = lane & 15, lq = lane >> 4;
  const int j0 = bx * 16;
  const int mw = wave * 32;
  const int r0 = mw + lrow, r1 = mw + 16 + lrow;

  const u16* bp[3];
#pragma unroll
  for (int t = 0; t < 3; ++t)
    bp[t] = Whh0s + (size_t)(t * HH + j0 + lrow) * 1024 + lq * 8;

  f32x4 acc[2][3];
#pragma unroll
  for (int i = 0; i < 2; ++i)
#pragma unroll
    for (int t = 0; t < 3; ++t) acc[i][t] = (f32x4){0.f, 0.f, 0.f, 0.f};

  for (int kc = 0; kc < 4; ++kc) {
    const int ks0 = kc * 128;
    stage128(SM, As, ks0);
    __syncthreads();
#pragma unroll
    for (int ki = 0; ki < 4; ++ki) {
      const int sl = ki * 4 + lq;
      s16x8 a0h = ldl(SM, r0, sl), a0l = ldl(SM, r0, 16 + sl);
      s16x8 a1h = ldl(SM, r1, sl), a1l = ldl(SM, r1, 16 + sl);
#pragma unroll
      for (int t = 0; t < 3; ++t) {
        s16x8 bh = ldf(bp[t]), bl = ldf(bp[t] + 512); bp[t] += 32;
        acc[0][t] = MFMA16(a0h, bh, acc[0][t]);
        acc[0][t] = MFMA16(a0h, bl, acc[0][t]);
        acc[0][t] = MFMA16(a0l, bh, acc[0][t]);
        acc[1][t] = MFMA16(a1h, bh, acc[1][t]);
        acc[1][t] = MFMA16(a1h, bl, acc[1][t]);
        acc[1][t] = MFMA16(a1l, bh, acc[1][t]);
      }
    }
    __syncthreads();
  }

  const int c = j0 + lrow;
  const float bir = bih0[c], biz = bih0[HH + c], bin = bih0[2 * HH + c];
  const float bhr = bhh0[c], bhz = bhh0[HH + c], bhn = bhh0[2 * HH + c];
  const float wr0 = Wih0[(size_t)c * 2],            wr1 = Wih0[(size_t)c * 2 + 1];
  const float wz0 = Wih0[(size_t)(HH + c) * 2],     wz1 = Wih0[(size_t)(HH + c) * 2 + 1];
  const float wn0 = Wih0[(size_t)(2 * HH + c) * 2], wn1 = Wih0[(size_t)(2 * HH + c) * 2 + 1];
#pragma unroll
  for (int tm = 0; tm < 2; ++tm) {
#pragma unroll
    for (int r = 0; r < 4; ++r) {
      int m = mw + tm * 16 + lq * 4 + r;
      float x0 = x[((size_t)m * SS + p) * 2];
      float x1 = x[((size_t)m * SS + p) * 2 + 1];
      float ir  = bir + x0 * wr0 + x1 * wr1;
      float iz  = biz + x0 * wz0 + x1 * wz1;
      float inn = bin + x0 * wn0 + x1 * wn1;
      float hr = acc[tm][0][r] + bhr, hz = acc[tm][1][r] + bhz, hn = acc[tm][2][r] + bhn;
      float rr = sigm(ir + hr);
      float zz = sigm(iz + hz);
      float nn = tanhf(inn + rr * hn);
      float hp = af[(size_t)m * HH + c];      // same-thread RMW
      float hv = (1.f - zz) * nn + zz * hp;
      af[(size_t)m * HH + c] = hv;
      u16 hi = f2b(hv);
      st16c(&as_new[(size_t)m * 1024 + c], hi);
      st16c(&as_new[(size_t)m * 1024 + 512 + c], f2b(hv - b2f(hi)));
    }
  }
}

// sim[s][b] = dot(out_enc[b,s,:], n1[b,:]). b = bx>>1, s-half = bx&1.
// n1f (cf) is cross-block -> bulk MALL loads; oe read-only cached.
__device__ __forceinline__ void sim_block(
    int bx, const float* __restrict__ n1f, const u16* __restrict__ oe,
    float* __restrict__ simt)
{
  const int b = bx >> 1, sc = bx & 1;
  const int wave = threadIdx.x >> 6, lane = threadIdx.x & 63;
  float xr[8];
  const u64* xp = (const u64*)(n1f + (size_t)b * HH + lane * 8);
#pragma unroll
  for (int j = 0; j < 4; ++j) {
    union { u64 q; float f[2]; } u; u.q = ld64c(xp + j);
    xr[2 * j] = u.f[0]; xr[2 * j + 1] = u.f[1];
  }
  int s0 = sc * 256 + wave * 64;
  for (int i = 0; i < 64; ++i) {
    int s = s0 + i;
    s16x8 ov = *(const s16x8*)(oe + ((size_t)b * SS + s) * HH + lane * 8);
    float acc = 0.f;
#pragma unroll
    for (int j = 0; j < 8; ++j) acc += xr[j] * b2f((u16)ov[j]);
    for (int off = 32; off; off >>= 1) acc += __shfl_down(acc, off);
    if (lane == 0) stf32c(&simt[(size_t)s * BB + b], acc);
  }
}

// Per-s softmax stats over batch dim (reference dim=0 quirk), computed ONCE.
// 128 blocks x 4 waves; wave handles row s = bx*4 + wave (128 b-values).
__device__ __forceinline__ void smax_block(int bx, const float* __restrict__ simt)
{
  const int wave = threadIdx.x >> 6, lane = threadIdx.x & 63;
  const int s = bx * 4 + wave;
  union { u64 q; float f[2]; } u;
  u.q = ld64c((const u64*)&simt[(size_t)s * BB + lane * 2]);
  float mx = fmaxf(u.f[0], u.f[1]);
  for (int off = 32; off; off >>= 1) mx = fmaxf(mx, __shfl_xor(mx, off));
  float e = expf(u.f[0] - mx) + expf(u.f[1] - mx);
  for (int off = 32; off; off >>= 1) e += __shfl_xor(e, off);
  if (lane == 0) { stf32c(&g_smx[s], mx); stf32c(&g_ssum[s], e); }
}

// attention -> logits -> argmax feedback. One block per batch element.
__device__ __forceinline__ void attn_block(
    int b, int tstep, const float* __restrict__ simt, const float* __restrict__ n1f,
    const u16* __restrict__ oe, const float* __restrict__ fcW,
    const float* __restrict__ fcb, float* __restrict__ dout,
    int* __restrict__ tok)
{
  __shared__ float wsm[SS];
  __shared__ float xv[2 * HH];
  __shared__ float lg[32];
  const int t = threadIdx.x;

  for (int s = t; s < SS; s += 256) {
    float sv = ldf32c(&simt[(size_t)s * BB + b]);
    float mx = ldf32c(&g_smx[s]);
    float sm = ldf32c(&g_ssum[s]);
    wsm[s] = expf(sv - mx) / sm;
  }
  xv[t]       = ldf32c(&n1f[(size_t)b * HH + t]);
  xv[t + 256] = ldf32c(&n1f[(size_t)b * HH + t + 256]);
  __syncthreads();

  {
    float a0 = 0.f, a1 = 0.f;
    const u16* base = oe + (size_t)b * SS * HH;   // read-only: cached
    for (int s = 0; s < SS; ++s) {
      float w = wsm[s];
      a0 += w * b2f(base[(size_t)s * HH + t]);
      a1 += w * b2f(base[(size_t)s * HH + t + 256]);
    }
    xv[HH + t]       = a0;
    xv[HH + t + 256] = a1;
  }
  __syncthreads();

  int wave = t >> 6, lane = t & 63;
  for (int v = wave; v < VV; v += 4) {
    const float* wr = fcW + (size_t)v * (2 * HH);
    float acc = 0.f;
#pragma unroll
    for (int i = 0; i < 16; ++i) acc += xv[i * 64 + lane] * wr[i * 64 + lane];
    for (int off = 32; off; off >>= 1) acc += __shfl_down(acc, off);
    if (lane == 0) {
      float lv = acc + fcb[v];
      lg[v] = lv;
      dout[(size_t)b * (TT * VV) + (size_t)tstep * VV + v] = lv;  // host-read
    }
  }
  __syncthreads();

  if (t == 0) {
    float best = lg[0]; int bi = 0;
    for (int v = 1; v < VV; ++v) if (lg[v] > best) { best = lg[v]; bi = v; }
    sti32c(&tok[b], bi);
  }
}

// =====================================================================
// Persistent encoder: 96 blocks, 513 phases, dataflow counters.
// l0@p: needs own p-1 (C_L0>=32p) + l1 p-1 done with shared buffer
// (C_L1>=64(p-1)). l1@p: needs pa from l0 p-1 + own p-1. They overlap.
// =====================================================================
__global__ __launch_bounds__(256) void enc_persist(
    const float* __restrict__ x, const float* __restrict__ Wih0,
    const u16* __restrict__ Whh0s,
    const float* __restrict__ bih0, const float* __restrict__ bhh0,
    const u16* __restrict__ Wih1s, const u16* __restrict__ Whh1s,
    const float* __restrict__ bih1, const float* __restrict__ bhh1,
    u16* ABF0, u16* ABF1, float* af,
    u16* CBF0, u16* CBF1, float* cf,
    u16* out_enc)
{
  __shared__ u16 SM[32768];
  const int bx = blockIdx.x;
  const u16* pa = ABF0; u16* pa_n = ABF1;
  const u16* pc = CBF0; u16* pc_n = CBF1;
  for (int p = 0; p <= SS; ++p) {
    waitc2(C_L0, 32 * p, C_L1, 64 * (p - 1));
    if (bx < 32) {
      if (p < SS) {
        gru_l0_staged(bx, p, SM, x, Wih0, Whh0s, bih0, bhh0, pa, af, pa_n);
        arrive(C_L0);
      }
    } else {
      if (p > 0) {
        u16* oe = out_enc + (size_t)(p - 1) * HH;
        gru_dual_staged<false, false>(bx - 32, SM, pa, nullptr, pc,
                                      Wih1s, Whh1s, bih1, bhh1,
                                      cf, pc_n, oe, (size_t)SS * HH);
        arrive(C_L1);
      }
    }
    const u16* tp;
    tp = pa; pa = pa_n; pa_n = (u16*)tp;
    tp = pc; pc = pc_n; pc_n = (u16*)tp;
  }
}

// =====================================================================
// Persistent decoder: 256 blocks, 64 steps x 5 dataflow phases.
// =====================================================================
__global__ __launch_bounds__(256) void dec_persist(
    const u16* __restrict__ EMBs, int* tok,
    const u16* __restrict__ WdIH0, const u16* __restrict__ WdHH0,
    const float* __restrict__ dbih0, const float* __restrict__ dbhh0,
    const u16* __restrict__ WdIH1, const u16* __restrict__ WdHH1,
    const float* __restrict__ dbih1, const float* __restrict__ dbhh1,
    float* af, float* cf,
    u16* D0A, u16* D0B, u16* D1A, u16* D1B,
    const u16* __restrict__ oe, float* simt,
    const float* __restrict__ fcW, const float* __restrict__ fcb,
    float* dout)
{
  __shared__ u16 SM[32768];
  const int bx = blockIdx.x;
  const u16* d0c = D0A; u16* d0n = D0B;
  const u16* d1c = D1A; u16* d1n = D1B;
  for (int t = 0; t < TT; ++t) {
    if (bx < 64) {
      waitc3(C_G0, 64 * t, C_ATT, 128 * t, C_G1, 64 * (t - 1));
      gru_dual_staged<true, false>(bx, SM, EMBs, tok, d0c,
                                   WdIH0, WdHH0, dbih0, dbhh0, af, d0n,
                                   nullptr, 0);
      arrive(C_G0);
    }
    { const u16* tp = d0c; d0c = d0n; d0n = (u16*)tp; }

    if (bx < 64) {
      waitc4(C_G0, 64 * (t + 1), C_G1, 64 * t, C_SIM, 256 * t, C_ATT, 128 * t);
      gru_dual_staged<false, true>(bx, SM, d0c, nullptr, d1c,
                                   WdIH1, WdHH1, dbih1, dbhh1, cf, d1n,
                                   nullptr, 0);
      arrive(C_G1);
    }
    { const u16* tp = d1c; d1c = d1n; d1n = (u16*)tp; }

    waitc3(C_G1, 64 * (t + 1), C_SMX, 128 * t, C_ATT, 128 * t);
    sim_block(bx, cf, oe, simt);
    arrive(C_SIM);

    if (bx < 128) {
      waitc2(C_SIM, 256 * (t + 1), C_ATT, 128 * t);
      smax_block(bx, simt);
      arrive(C_SMX);
    }

    if (bx < BB) {
      waitc4(C_SMX, 128 * (t + 1), C_SIM, 256 * (t + 1),
             C_G1, 64 * (t + 1), C_G0, 64 * (t + 1));
      attn_block(bx, t, simt, cf, oe, fcW, fcb, dout, tok);
      arrive(C_ATT);
    }
  }
}

// Split all 7 weight matrices + embedding in one launch.
__global__ __launch_bounds__(256) void splitall(
    const float* __restrict__ s0, u16* d0, const float* __restrict__ s1, u16* d1,
    const float* __restrict__ s2, u16* d2, const float* __restrict__ s3, u16* d3,
    const float* __restrict__ s4, u16* d4, const float* __restrict__ s5, u16* d5,
    const float* __restrict__ s6, u16* d6, const float* __restrict__ s7, u16* d7)
{
  const int WN = 3 * HH * HH;  // 786432
  int i = blockIdx.x * 256 + threadIdx.x;
  const float* s; u16* d; int j;
  if      (i < 1 * WN) { s = s0; d = d0; j = i; }
  else if (i < 2 * WN) { s = s1; d = d1; j = i - 1 * WN; }
  else if (i < 3 * WN) { s = s2; d = d2; j = i - 2 * WN; }
  else if (i < 4 * WN) { s = s3; d = d3; j = i - 3 * WN; }
  else if (i < 5 * WN) { s = s4; d = d4; j = i - 4 * WN; }
  else if (i < 6 * WN) { s = s5; d = d5; j = i - 5 * WN; }
  else if (i < 7 * WN) { s = s6; d = d6; j = i - 6 * WN; }
  else { j = i - 7 * WN; if (j >= VV * HH) return; s = s7; d = d7; }
  int r = j >> 9, k = j & 511;
  float v = s[j];
  u16 hi = f2b(v);
  d[(size_t)r * 1024 + k]       = hi;
  d[(size_t)r * 1024 + 512 + k] = f2b(v - b2f(hi));
}

__global__ __launch_bounds__(256) void initk(
    float* af, float* cf, u16* b0, u16* b1, u16* b2, u16* b3, int* tok)
{
  int i = blockIdx.x * 256 + threadIdx.x;   // 131072 threads
  b0[i] = 0; b1[i] = 0; b2[i] = 0; b3[i] = 0;
  if (i < BB * HH) { af[i] = 0.f; cf[i] = 0.f; }
  if (i < BB) tok[i] = 0;
  if (i < 8) g_cnt[i] = 0;
}

__global__ __launch_bounds__(256) void finalize(
    const float* __restrict__ d0, const float* __restrict__ d1,
    float* __restrict__ oh)
{
  int i = blockIdx.x * 256 + threadIdx.x;
  oh[i]           = d0[i];
  oh[BB * HH + i] = d1[i];
}

extern "C" void kernel_launch(void* const* d_in, const int* in_sizes, int n_in,
                              void* d_out, int out_size, void* d_ws, size_t ws_size,
                              hipStream_t stream) {
  const float* x     = (const float*)d_in[0];
  const float* emb   = (const float*)d_in[1];
  const float* eWih0 = (const float*)d_in[2];
  const float* eWhh0 = (const float*)d_in[3];
  const float* ebih0 = (const float*)d_in[4];
  const float* ebhh0 = (const float*)d_in[5];
  const float* eWih1 = (const float*)d_in[6];
  const float* eWhh1 = (const float*)d_in[7];
  const float* ebih1 = (const float*)d_in[8];
  const float* ebhh1 = (const float*)d_in[9];
  const float* dWih0 = (const float*)d_in[10];
  const float* dWhh0 = (const float*)d_in[11];
  const float* dbih0 = (const float*)d_in[12];
  const float* dbhh0 = (const float*)d_in[13];
  const float* dWih1 = (const float*)d_in[14];
  const float* dWhh1 = (const float*)d_in[15];
  const float* dbih1 = (const float*)d_in[16];
  const float* dbhh1 = (const float*)d_in[17];
  const float* fcW   = (const float*)d_in[18];
  const float* fcb   = (const float*)d_in[19];
  float* dout = (float*)d_out;

  char* wsb = (char*)d_ws;
  float* af   = (float*)(wsb + 0);          // 128x512 f32 (a / d0 state, RMW)
  float* cf   = (float*)(wsb + 262144);     // 128x512 f32 (c / d1 state, RMW)
  u16* ABF0   = (u16*)(wsb + 524288);       // split states 128x1024 u16 each
  u16* ABF1   = (u16*)(wsb + 786432);
  u16* CBF0   = (u16*)(wsb + 1048576);
  u16* CBF1   = (u16*)(wsb + 1310720);
  int* tok    = (int*)(wsb + 1572864);
  float* simt = (float*)(wsb + 1573376);    // [S][B] f32, 256 KB
  u16* WeHH0  = (u16*)(wsb + 1835520);      // split weights, 3 MB each
  u16* WeIH1  = (u16*)(wsb + 4981248);
  u16* WeHH1  = (u16*)(wsb + 8126976);
  u16* WdIH0  = (u16*)(wsb + 11272704);
  u16* WdHH0  = (u16*)(wsb + 14418432);
  u16* WdIH1  = (u16*)(wsb + 17564160);
  u16* WdHH1  = (u16*)(wsb + 20709888);
  u16* EMBs   = (u16*)(wsb + 23855616);     // 30x1024 u16
  u16* oe     = (u16*)(wsb + 23917056);     // out_enc bf16 [B][S][H], 64 MiB

  initk<<<512, 256, 0, stream>>>(af, cf, ABF0, ABF1, CBF0, CBF1, tok);

  splitall<<<21564, 256, 0, stream>>>(eWhh0, WeHH0, eWih1, WeIH1, eWhh1, WeHH1,
                                      dWih0, WdIH0, dWhh0, WdHH0, dWih1, WdIH1,
                                      dWhh1, WdHH1, emb, EMBs);

  enc_persist<<<96, 256, 0, stream>>>(x, eWih0, WeHH0, ebih0, ebhh0,
                                      WeIH1, WeHH1, ebih1, ebhh1,
                                      ABF0, ABF1, af, CBF0, CBF1, cf, oe);

  // a_511 split in ABF0 (written p=511); c_511 split in CBF1 (written p=512)
  dec_persist<<<256, 256, 0, stream>>>(EMBs, tok, WdIH0, WdHH0, dbih0, dbhh0,
                                       WdIH1, WdHH1, dbih1, dbhh1,
                                       af, cf, ABF0, ABF1, CBF1, CBF0,
                                       oe, simt, fcW, fcb, dout);

  finalize<<<256, 256, 0, stream>>>(af, cf, dout + (size_t)BB * TT * VV);
}

// Round 7
// 33844.504 us; speedup vs baseline: 1.0747x; 1.0034x over previous
//
#include <hip/hip_runtime.h>
#include <math.h>

typedef short  s16x8 __attribute__((ext_vector_type(8)));
typedef float  f32x4 __attribute__((ext_vector_type(4)));
typedef unsigned short u16;
typedef unsigned long long u64;

#define MFMA16(a, b, c) __builtin_amdgcn_mfma_f32_16x16x32_bf16((a), (b), (c), 0, 0, 0)

#define BB 128
#define SS 512
#define HH 512
#define VV 30
#define TT 64

#define SC_SYS  __HIP_MEMORY_SCOPE_SYSTEM
#define SC_AGT  __HIP_MEMORY_SCOPE_AGENT

__device__ __forceinline__ float b2f(u16 v) {
  union { unsigned int u; float f; } c; c.u = ((unsigned int)v) << 16; return c.f;
}
__device__ __forceinline__ u16 f2b(float f) {
  union { float f; unsigned int u; } c; c.f = f;
  unsigned int r = (c.u + 0x7FFFu + ((c.u >> 16) & 1u)) >> 16;
  return (u16)r;
}
__device__ __forceinline__ float sigm(float x) { return 1.f / (1.f + expf(-x)); }
__device__ __forceinline__ s16x8 ldf(const u16* p) { return *(const s16x8*)p; }

// ---- coherent (MALL-level) helpers: ONLY for data crossing block
// boundaries inside a persistent kernel. Relaxed -> no L2 wb/inv walks.
__device__ __forceinline__ u64  ld64c(const u64* p)      { return __hip_atomic_load(p, __ATOMIC_RELAXED, SC_SYS); }
__device__ __forceinline__ void st16c(u16* p, u16 v)     { __hip_atomic_store(p, v, __ATOMIC_RELAXED, SC_SYS); }
__device__ __forceinline__ void stf32c(float* p, float v){ __hip_atomic_store(p, v, __ATOMIC_RELAXED, SC_SYS); }
__device__ __forceinline__ float ldf32c(const float* p)  { return __hip_atomic_load(p, __ATOMIC_RELAXED, SC_SYS); }
__device__ __forceinline__ void sti32c(int* p, int v)    { __hip_atomic_store(p, v, __ATOMIC_RELAXED, SC_SYS); }
__device__ __forceinline__ int  ldi32c(const int* p)     { return __hip_atomic_load(p, __ATOMIC_RELAXED, SC_SYS); }

// ---------------------------------------------------------------------
// Dataflow synchronization: per-producer-group monotone counters.
// CRITICAL (R6 post-mortem): counters must be SYSTEM scope end-to-end.
// Agent-scope polls can be served by the polling XCD's non-coherent L2
// and spin on a stale line until eviction (~40us) — the measured cost of
// every handoff in R2..R6. System-scope (sc0|sc1) polls are served at
// the MALL where the fetch_add lands -> ~us-scale propagation.
// waitp(): relaxed poll + timeout (pathological hang -> terminating run).
// ---------------------------------------------------------------------
__device__ unsigned int g_cnt[8];
__device__ float g_smx[SS], g_ssum[SS];

#define C_L0 0
#define C_L1 1
#define C_G0 2
#define C_G1 3
#define C_SIM 4
#define C_SMX 5
#define C_ATT 6

__device__ __forceinline__ void waitp(int idx, int target) {
  if (target <= 0) return;
  unsigned long long t0 = __builtin_amdgcn_s_memrealtime();
  while ((int)__hip_atomic_load(&g_cnt[idx], __ATOMIC_RELAXED, SC_SYS) < target) {
    __builtin_amdgcn_s_sleep(1);
    if (__builtin_amdgcn_s_memrealtime() - t0 > (1ull << 21)) break;
  }
}
__device__ __forceinline__ void waitc2(int i1, int t1, int i2, int t2) {
  if (threadIdx.x == 0) { waitp(i1, t1); waitp(i2, t2); }
  __syncthreads();
}
__device__ __forceinline__ void waitc3(int i1, int t1, int i2, int t2, int i3, int t3) {
  if (threadIdx.x == 0) { waitp(i1, t1); waitp(i2, t2); waitp(i3, t3); }
  __syncthreads();
}
__device__ __forceinline__ void waitc4(int i1, int t1, int i2, int t2, int i3, int t3, int i4, int t4) {
  if (threadIdx.x == 0) { waitp(i1, t1); waitp(i2, t2); waitp(i3, t3); waitp(i4, t4); }
  __syncthreads();
}
__device__ __forceinline__ void arrive(int idx) {
  __syncthreads();
  if (threadIdx.x == 0) {
    asm volatile("s_waitcnt vmcnt(0) lgkmcnt(0)" ::: "memory");
    __hip_atomic_fetch_add(&g_cnt[idx], 1u, __ATOMIC_RELAXED, SC_SYS);
  }
}

// ---------------------------------------------------------------------
// LDS staging of split-format state (rows x [hi128|lo128] u16 K-chunks).
// Row r = 512B = 32 slots of 16B; slot s stored at (s ^ (r&7)) -> XOR
// swizzle keeps ds_read_b128 at the free 2-way aliasing level.
// Bulk ld64c batches amortize MALL latency.
// ---------------------------------------------------------------------
__device__ __forceinline__ s16x8 ldl(const u16* SM, int row, int slot) {
  return *(const s16x8*)&SM[(row << 8) + ((slot ^ (row & 7)) << 3)];
}

// 2 sources x 64 rows (enc-l1 / dec-gru1): src = tid>>7, r = (tid>>1)&63, h = tid&1
__device__ __forceinline__ void stage64_2(u16* SM, const u16* A1, const u16* A2,
                                          int mbase, int ks0) {
  const int t = threadIdx.x;
  const int src = t >> 7, r = (t >> 1) & 63, h = t & 1;
  const u16* gp = (src ? A2 : A1) + (size_t)(mbase + r) * 1024 + ks0 + h * 64;
  u64 th_[16], tl_[16];
#pragma unroll
  for (int j = 0; j < 16; ++j) th_[j] = ld64c((const u64*)gp + j);
#pragma unroll
  for (int j = 0; j < 16; ++j) tl_[j] = ld64c((const u64*)(gp + 512) + j);
  u16* Lb = SM + ((src * 64 + r) << 8);
  const int rx = r & 7;
#pragma unroll
  for (int j = 0; j < 16; ++j) {
    const int sl = h * 8 + (j >> 1);
    *(u64*)&Lb[((sl ^ rx) << 3) + ((j & 1) << 2)]        = th_[j];
    *(u64*)&Lb[(((16 + sl) ^ rx) << 3) + ((j & 1) << 2)] = tl_[j];
  }
}

// 1 source x 64 rows into rows 64..127 (dec-gru0 a2): r = (tid>>2)&63, q = tid&3
__device__ __forceinline__ void stage64_1(u16* SM, const u16* A2, int mbase, int ks0) {
  const int t = threadIdx.x;
  const int r = (t >> 2) & 63, q = t & 3;
  const u16* gp = A2 + (size_t)(mbase + r) * 1024 + ks0 + q * 32;
  u64 th_[8], tl_[8];
#pragma unroll
  for (int j = 0; j < 8; ++j) th_[j] = ld64c((const u64*)gp + j);
#pragma unroll
  for (int j = 0; j < 8; ++j) tl_[j] = ld64c((const u64*)(gp + 512) + j);
  u16* Lb = SM + ((64 + r) << 8);
  const int rx = r & 7;
#pragma unroll
  for (int j = 0; j < 8; ++j) {
    const int sl = q * 4 + (j >> 1);
    *(u64*)&Lb[((sl ^ rx) << 3) + ((j & 1) << 2)]        = th_[j];
    *(u64*)&Lb[(((16 + sl) ^ rx) << 3) + ((j & 1) << 2)] = tl_[j];
  }
}

// 1 source x 128 rows (enc-l0): r = tid>>1, h = tid&1
__device__ __forceinline__ void stage128(u16* SM, const u16* As, int ks0) {
  const int t = threadIdx.x;
  const int r = t >> 1, h = t & 1;
  const u16* gp = As + (size_t)r * 1024 + ks0 + h * 64;
  u64 th_[16], tl_[16];
#pragma unroll
  for (int j = 0; j < 16; ++j) th_[j] = ld64c((const u64*)gp + j);
#pragma unroll
  for (int j = 0; j < 16; ++j) tl_[j] = ld64c((const u64*)(gp + 512) + j);
  u16* Lb = SM + (r << 8);
  const int rx = r & 7;
#pragma unroll
  for (int j = 0; j < 16; ++j) {
    const int sl = h * 8 + (j >> 1);
    *(u64*)&Lb[((sl ^ rx) << 3) + ((j & 1) << 2)]        = th_[j];
    *(u64*)&Lb[(((16 + sl) ^ rx) << 3) + ((j & 1) << 2)] = tl_[j];
  }
}

// Split-f32 format: per logical row of K=512, u16 row of 1024: [hi x512 | lo x512].
// hi = bf16(v), lo = bf16(v - hi). GEMM does hi*hi + hi*lo + lo*hi (Markidis).

// =====================================================================
// Dual-input GRU cell (enc-l1 / decoder): 64 block-roles x 256 thr.
// GATHER: a1 = EMBs[gather[m]] via plain cached loads (read-only);
// otherwise a1 staged. a2 always staged. Weights plain cached (L2-warm).
// =====================================================================
template <bool GATHER, bool COH_H>
__device__ __forceinline__ void gru_dual_staged(
    int bx, u16* SM,
    const u16* __restrict__ A1s, const int* __restrict__ gather,
    const u16* __restrict__ A2s,
    const u16* __restrict__ Wihs, const u16* __restrict__ Whhs,
    const float* __restrict__ bih, const float* __restrict__ bhh,
    float* __restrict__ hf, u16* __restrict__ hs_new,
    u16* __restrict__ oe, size_t oe_mstride)
{
  const int tid  = threadIdx.x;
  const int wave = tid >> 6, lane = tid & 63;
  const int lrow = lane & 15, lq = lane >> 4;
  const int j0 = (bx >> 1) * 16;
  const int mbase = (bx & 1) * 64;
  const int lr = wave * 16 + lrow;       // local row 0..63
  const int m0 = mbase + wave * 16;

  const u16* a1p = nullptr;
  if (GATHER)
    a1p = A1s + (size_t)ldi32c(&gather[m0 + lrow]) * 1024 + lq * 8;

  const u16* bp[6];
#pragma unroll
  for (int t = 0; t < 6; ++t) {
    int g = (t < 3) ? t : t - 3;
    const u16* W = (t < 3) ? Wihs : Whhs;
    bp[t] = W + (size_t)(g * HH + j0 + lrow) * 1024 + lq * 8;
  }

  f32x4 acc[6];
#pragma unroll
  for (int t = 0; t < 6; ++t) acc[t] = (f32x4){0.f, 0.f, 0.f, 0.f};

  for (int kc = 0; kc < 4; ++kc) {
    const int ks0 = kc * 128;
    if (GATHER) stage64_1(SM, A2s, mbase, ks0);
    else        stage64_2(SM, A1s, A2s, mbase, ks0);
    __syncthreads();
#pragma unroll
    for (int ki = 0; ki < 4; ++ki) {
      const int sl = ki * 4 + lq;
      s16x8 a1h, a1l;
      if (GATHER) { a1h = ldf(a1p); a1l = ldf(a1p + 512); a1p += 32; }
      else        { a1h = ldl(SM, lr, sl); a1l = ldl(SM, lr, 16 + sl); }
      s16x8 a2h = ldl(SM, 64 + lr, sl), a2l = ldl(SM, 64 + lr, 16 + sl);
#pragma unroll
      for (int t = 0; t < 6; ++t) {
        s16x8 bh = ldf(bp[t]), bl = ldf(bp[t] + 512); bp[t] += 32;
        s16x8 ah = (t < 3) ? a1h : a2h;
        s16x8 al = (t < 3) ? a1l : a2l;
        acc[t] = MFMA16(ah, bh, acc[t]);
        acc[t] = MFMA16(ah, bl, acc[t]);
        acc[t] = MFMA16(al, bh, acc[t]);
      }
    }
    __syncthreads();
  }

  const int c = j0 + lrow;
  const float bir = bih[c], biz = bih[HH + c], bin = bih[2 * HH + c];
  const float bhr = bhh[c], bhz = bhh[HH + c], bhn = bhh[2 * HH + c];
#pragma unroll
  for (int r = 0; r < 4; ++r) {
    int m = mbase + wave * 16 + lq * 4 + r;
    float ir = acc[0][r] + bir, iz = acc[1][r] + biz, inn = acc[2][r] + bin;
    float hr = acc[3][r] + bhr, hz = acc[4][r] + bhz, hn = acc[5][r] + bhn;
    float rr = sigm(ir + hr);
    float zz = sigm(iz + hz);
    float nn = tanhf(inn + rr * hn);
    float hp = COH_H ? ldf32c(&hf[(size_t)m * HH + c]) : hf[(size_t)m * HH + c];
    float hv = (1.f - zz) * nn + zz * hp;
    if (COH_H) stf32c(&hf[(size_t)m * HH + c], hv);
    else       hf[(size_t)m * HH + c] = hv;
    u16 hi = f2b(hv);
    st16c(&hs_new[(size_t)m * 1024 + c], hi);
    st16c(&hs_new[(size_t)m * 1024 + 512 + c], f2b(hv - b2f(hi)));
    if (oe) oe[(size_t)m * oe_mstride + c] = hi;   // read only by next kernel
  }
}

// Encoder layer-0: gh via MFMA (staged split A, cached split Whh0); gi inline f32.
__device__ __forceinline__ void gru_l0_staged(
    int bx, int p, u16* SM,
    const float* __restrict__ x, const float* __restrict__ Wih0,
    const u16* __restrict__ Whh0s,
    const float* __restrict__ bih0, const float* __restrict__ bhh0,
    const u16* __restrict__ As,
    float* __restrict__ af, u16* __restrict__ as_new)
{
  const int tid  = threadIdx.x;
  const int wave = tid >> 6, lane = tid & 63;
  const int lrow = lane & 15, lq = lane >> 4;
  const int j0 = bx * 16;
  const int mw = wave * 32;
  const int r0 = mw + lrow, r1 = mw + 16 + lrow;

  const u16* bp[3];
#pragma unroll
  for (int t = 0; t < 3; ++t)
    bp[t] = Whh0s + (size_t)(t * HH + j0 + lrow) * 1024 + lq * 8;

  f32x4 acc[2][3];
#pragma unroll
  for (int i = 0; i < 2; ++i)
#pragma unroll
    for (int t = 0; t < 3; ++t) acc[i][t] = (f32x4){0.f, 0.f, 0.f, 0.f};

  for (int kc = 0; kc < 4; ++kc) {
    const int ks0 = kc * 128;
    stage128(SM, As, ks0);
    __syncthreads();
#pragma unroll
    for (int ki = 0; ki < 4; ++ki) {
      const int sl = ki * 4 + lq;
      s16x8 a0h = ldl(SM, r0, sl), a0l = ldl(SM, r0, 16 + sl);
      s16x8 a1h = ldl(SM, r1, sl), a1l = ldl(SM, r1, 16 + sl);
#pragma unroll
      for (int t = 0; t < 3; ++t) {
        s16x8 bh = ldf(bp[t]), bl = ldf(bp[t] + 512); bp[t] += 32;
        acc[0][t] = MFMA16(a0h, bh, acc[0][t]);
        acc[0][t] = MFMA16(a0h, bl, acc[0][t]);
        acc[0][t] = MFMA16(a0l, bh, acc[0][t]);
        acc[1][t] = MFMA16(a1h, bh, acc[1][t]);
        acc[1][t] = MFMA16(a1h, bl, acc[1][t]);
        acc[1][t] = MFMA16(a1l, bh, acc[1][t]);
      }
    }
    __syncthreads();
  }

  const int c = j0 + lrow;
  const float bir = bih0[c], biz = bih0[HH + c], bin = bih0[2 * HH + c];
  const float bhr = bhh0[c], bhz = bhh0[HH + c], bhn = bhh0[2 * HH + c];
  const float wr0 = Wih0[(size_t)c * 2],            wr1 = Wih0[(size_t)c * 2 + 1];
  const float wz0 = Wih0[(size_t)(HH + c) * 2],     wz1 = Wih0[(size_t)(HH + c) * 2 + 1];
  const float wn0 = Wih0[(size_t)(2 * HH + c) * 2], wn1 = Wih0[(size_t)(2 * HH + c) * 2 + 1];
#pragma unroll
  for (int tm = 0; tm < 2; ++tm) {
#pragma unroll
    for (int r = 0; r < 4; ++r) {
      int m = mw + tm * 16 + lq * 4 + r;
      float x0 = x[((size_t)m * SS + p) * 2];
      float x1 = x[((size_t)m * SS + p) * 2 + 1];
      float ir  = bir + x0 * wr0 + x1 * wr1;
      float iz  = biz + x0 * wz0 + x1 * wz1;
      float inn = bin + x0 * wn0 + x1 * wn1;
      float hr = acc[tm][0][r] + bhr, hz = acc[tm][1][r] + bhz, hn = acc[tm][2][r] + bhn;
      float rr = sigm(ir + hr);
      float zz = sigm(iz + hz);
      float nn = tanhf(inn + rr * hn);
      float hp = af[(size_t)m * HH + c];      // same-thread RMW
      float hv = (1.f - zz) * nn + zz * hp;
      af[(size_t)m * HH + c] = hv;
      u16 hi = f2b(hv);
      st16c(&as_new[(size_t)m * 1024 + c], hi);
      st16c(&as_new[(size_t)m * 1024 + 512 + c], f2b(hv - b2f(hi)));
    }
  }
}

// sim[s][b] = dot(out_enc[b,s,:], n1[b,:]). b = bx>>1, s-half = bx&1.
// n1f (cf) is cross-block -> bulk MALL loads; oe read-only cached.
__device__ __forceinline__ void sim_block(
    int bx, const float* __restrict__ n1f, const u16* __restrict__ oe,
    float* __restrict__ simt)
{
  const int b = bx >> 1, sc = bx & 1;
  const int wave = threadIdx.x >> 6, lane = threadIdx.x & 63;
  float xr[8];
  const u64* xp = (const u64*)(n1f + (size_t)b * HH + lane * 8);
#pragma unroll
  for (int j = 0; j < 4; ++j) {
    union { u64 q; float f[2]; } u; u.q = ld64c(xp + j);
    xr[2 * j] = u.f[0]; xr[2 * j + 1] = u.f[1];
  }
  int s0 = sc * 256 + wave * 64;
  for (int i = 0; i < 64; ++i) {
    int s = s0 + i;
    s16x8 ov = *(const s16x8*)(oe + ((size_t)b * SS + s) * HH + lane * 8);
    float acc = 0.f;
#pragma unroll
    for (int j = 0; j < 8; ++j) acc += xr[j] * b2f((u16)ov[j]);
    for (int off = 32; off; off >>= 1) acc += __shfl_down(acc, off);
    if (lane == 0) stf32c(&simt[(size_t)s * BB + b], acc);
  }
}

// Per-s softmax stats over batch dim (reference dim=0 quirk), computed ONCE.
// 128 blocks x 4 waves; wave handles row s = bx*4 + wave (128 b-values).
__device__ __forceinline__ void smax_block(int bx, const float* __restrict__ simt)
{
  const int wave = threadIdx.x >> 6, lane = threadIdx.x & 63;
  const int s = bx * 4 + wave;
  union { u64 q; float f[2]; } u;
  u.q = ld64c((const u64*)&simt[(size_t)s * BB + lane * 2]);
  float mx = fmaxf(u.f[0], u.f[1]);
  for (int off = 32; off; off >>= 1) mx = fmaxf(mx, __shfl_xor(mx, off));
  float e = expf(u.f[0] - mx) + expf(u.f[1] - mx);
  for (int off = 32; off; off >>= 1) e += __shfl_xor(e, off);
  if (lane == 0) { stf32c(&g_smx[s], mx); stf32c(&g_ssum[s], e); }
}

// attention -> logits -> argmax feedback. One block per batch element.
__device__ __forceinline__ void attn_block(
    int b, int tstep, const float* __restrict__ simt, const float* __restrict__ n1f,
    const u16* __restrict__ oe, const float* __restrict__ fcW,
    const float* __restrict__ fcb, float* __restrict__ dout,
    int* __restrict__ tok)
{
  __shared__ float wsm[SS];
  __shared__ float xv[2 * HH];
  __shared__ float lg[32];
  const int t = threadIdx.x;

  for (int s = t; s < SS; s += 256) {
    float sv = ldf32c(&simt[(size_t)s * BB + b]);
    float mx = ldf32c(&g_smx[s]);
    float sm = ldf32c(&g_ssum[s]);
    wsm[s] = expf(sv - mx) / sm;
  }
  xv[t]       = ldf32c(&n1f[(size_t)b * HH + t]);
  xv[t + 256] = ldf32c(&n1f[(size_t)b * HH + t + 256]);
  __syncthreads();

  {
    float a0 = 0.f, a1 = 0.f;
    const u16* base = oe + (size_t)b * SS * HH;   // read-only: cached
    for (int s = 0; s < SS; ++s) {
      float w = wsm[s];
      a0 += w * b2f(base[(size_t)s * HH + t]);
      a1 += w * b2f(base[(size_t)s * HH + t + 256]);
    }
    xv[HH + t]       = a0;
    xv[HH + t + 256] = a1;
  }
  __syncthreads();

  int wave = t >> 6, lane = t & 63;
  for (int v = wave; v < VV; v += 4) {
    const float* wr = fcW + (size_t)v * (2 * HH);
    float acc = 0.f;
#pragma unroll
    for (int i = 0; i < 16; ++i) acc += xv[i * 64 + lane] * wr[i * 64 + lane];
    for (int off = 32; off; off >>= 1) acc += __shfl_down(acc, off);
    if (lane == 0) {
      float lv = acc + fcb[v];
      lg[v] = lv;
      dout[(size_t)b * (TT * VV) + (size_t)tstep * VV + v] = lv;  // host-read
    }
  }
  __syncthreads();

  if (t == 0) {
    float best = lg[0]; int bi = 0;
    for (int v = 1; v < VV; ++v) if (lg[v] > best) { best = lg[v]; bi = v; }
    sti32c(&tok[b], bi);
  }
}

// =====================================================================
// Persistent encoder: 96 blocks, 513 phases, dataflow counters.
// l0@p: needs own p-1 (C_L0>=32p) + l1 p-1 done with shared buffer
// (C_L1>=64(p-1)). l1@p: needs pa from l0 p-1 + own p-1. They overlap.
// =====================================================================
__global__ __launch_bounds__(256) void enc_persist(
    const float* __restrict__ x, const float* __restrict__ Wih0,
    const u16* __restrict__ Whh0s,
    const float* __restrict__ bih0, const float* __restrict__ bhh0,
    const u16* __restrict__ Wih1s, const u16* __restrict__ Whh1s,
    const float* __restrict__ bih1, const float* __restrict__ bhh1,
    u16* ABF0, u16* ABF1, float* af,
    u16* CBF0, u16* CBF1, float* cf,
    u16* out_enc)
{
  __shared__ u16 SM[32768];
  const int bx = blockIdx.x;
  const u16* pa = ABF0; u16* pa_n = ABF1;
  const u16* pc = CBF0; u16* pc_n = CBF1;
  for (int p = 0; p <= SS; ++p) {
    waitc2(C_L0, 32 * p, C_L1, 64 * (p - 1));
    if (bx < 32) {
      if (p < SS) {
        gru_l0_staged(bx, p, SM, x, Wih0, Whh0s, bih0, bhh0, pa, af, pa_n);
        arrive(C_L0);
      }
    } else {
      if (p > 0) {
        u16* oe = out_enc + (size_t)(p - 1) * HH;
        gru_dual_staged<false, false>(bx - 32, SM, pa, nullptr, pc,
                                      Wih1s, Whh1s, bih1, bhh1,
                                      cf, pc_n, oe, (size_t)SS * HH);
        arrive(C_L1);
      }
    }
    const u16* tp;
    tp = pa; pa = pa_n; pa_n = (u16*)tp;
    tp = pc; pc = pc_n; pc_n = (u16*)tp;
  }
}

// =====================================================================
// Persistent decoder: 256 blocks, 64 steps x 5 dataflow phases.
// =====================================================================
__global__ __launch_bounds__(256) void dec_persist(
    const u16* __restrict__ EMBs, int* tok,
    const u16* __restrict__ WdIH0, const u16* __restrict__ WdHH0,
    const float* __restrict__ dbih0, const float* __restrict__ dbhh0,
    const u16* __restrict__ WdIH1, const u16* __restrict__ WdHH1,
    const float* __restrict__ dbih1, const float* __restrict__ dbhh1,
    float* af, float* cf,
    u16* D0A, u16* D0B, u16* D1A, u16* D1B,
    const u16* __restrict__ oe, float* simt,
    const float* __restrict__ fcW, const float* __restrict__ fcb,
    float* dout)
{
  __shared__ u16 SM[32768];
  const int bx = blockIdx.x;
  const u16* d0c = D0A; u16* d0n = D0B;
  const u16* d1c = D1A; u16* d1n = D1B;
  for (int t = 0; t < TT; ++t) {
    if (bx < 64) {
      waitc3(C_G0, 64 * t, C_ATT, 128 * t, C_G1, 64 * (t - 1));
      gru_dual_staged<true, false>(bx, SM, EMBs, tok, d0c,
                                   WdIH0, WdHH0, dbih0, dbhh0, af, d0n,
                                   nullptr, 0);
      arrive(C_G0);
    }
    { const u16* tp = d0c; d0c = d0n; d0n = (u16*)tp; }

    if (bx < 64) {
      waitc4(C_G0, 64 * (t + 1), C_G1, 64 * t, C_SIM, 256 * t, C_ATT, 128 * t);
      gru_dual_staged<false, true>(bx, SM, d0c, nullptr, d1c,
                                   WdIH1, WdHH1, dbih1, dbhh1, cf, d1n,
                                   nullptr, 0);
      arrive(C_G1);
    }
    { const u16* tp = d1c; d1c = d1n; d1n = (u16*)tp; }

    waitc3(C_G1, 64 * (t + 1), C_SMX, 128 * t, C_ATT, 128 * t);
    sim_block(bx, cf, oe, simt);
    arrive(C_SIM);

    if (bx < 128) {
      waitc2(C_SIM, 256 * (t + 1), C_ATT, 128 * t);
      smax_block(bx, simt);
      arrive(C_SMX);
    }

    if (bx < BB) {
      waitc4(C_SMX, 128 * (t + 1), C_SIM, 256 * (t + 1),
             C_G1, 64 * (t + 1), C_G0, 64 * (t + 1));
      attn_block(bx, t, simt, cf, oe, fcW, fcb, dout, tok);
      arrive(C_ATT);
    }
  }
}

// Split all 7 weight matrices + embedding in one launch.
__global__ __launch_bounds__(256) void splitall(
    const float* __restrict__ s0, u16* d0, const float* __restrict__ s1, u16* d1,
    const float* __restrict__ s2, u16* d2, const float* __restrict__ s3, u16* d3,
    const float* __restrict__ s4, u16* d4, const float* __restrict__ s5, u16* d5,
    const float* __restrict__ s6, u16* d6, const float* __restrict__ s7, u16* d7)
{
  const int WN = 3 * HH * HH;  // 786432
  int i = blockIdx.x * 256 + threadIdx.x;
  const float* s; u16* d; int j;
  if      (i < 1 * WN) { s = s0; d = d0; j = i; }
  else if (i < 2 * WN) { s = s1; d = d1; j = i - 1 * WN; }
  else if (i < 3 * WN) { s = s2; d = d2; j = i - 2 * WN; }
  else if (i < 4 * WN) { s = s3; d = d3; j = i - 3 * WN; }
  else if (i < 5 * WN) { s = s4; d = d4; j = i - 4 * WN; }
  else if (i < 6 * WN) { s = s5; d = d5; j = i - 5 * WN; }
  else if (i < 7 * WN) { s = s6; d = d6; j = i - 6 * WN; }
  else { j = i - 7 * WN; if (j >= VV * HH) return; s = s7; d = d7; }
  int r = j >> 9, k = j & 511;
  float v = s[j];
  u16 hi = f2b(v);
  d[(size_t)r * 1024 + k]       = hi;
  d[(size_t)r * 1024 + 512 + k] = f2b(v - b2f(hi));
}

__global__ __launch_bounds__(256) void initk(
    float* af, float* cf, u16* b0, u16* b1, u16* b2, u16* b3, int* tok)
{
  int i = blockIdx.x * 256 + threadIdx.x;   // 131072 threads
  b0[i] = 0; b1[i] = 0; b2[i] = 0; b3[i] = 0;
  if (i < BB * HH) { af[i] = 0.f; cf[i] = 0.f; }
  if (i < BB) tok[i] = 0;
  if (i < 8) g_cnt[i] = 0;
}

__global__ __launch_bounds__(256) void finalize(
    const float* __restrict__ d0, const float* __restrict__ d1,
    float* __restrict__ oh)
{
  int i = blockIdx.x * 256 + threadIdx.x;
  oh[i]           = d0[i];
  oh[BB * HH + i] = d1[i];
}

extern "C" void kernel_launch(void* const* d_in, const int* in_sizes, int n_in,
                              void* d_out, int out_size, void* d_ws, size_t ws_size,
                              hipStream_t stream) {
  const float* x     = (const float*)d_in[0];
  const float* emb   = (const float*)d_in[1];
  const float* eWih0 = (const float*)d_in[2];
  const float* eWhh0 = (const float*)d_in[3];
  const float* ebih0 = (const float*)d_in[4];
  const float* ebhh0 = (const float*)d_in[5];
  const float* eWih1 = (const float*)d_in[6];
  const float* eWhh1 = (const float*)d_in[7];
  const float* ebih1 = (const float*)d_in[8];
  const float* ebhh1 = (const float*)d_in[9];
  const float* dWih0 = (const float*)d_in[10];
  const float* dWhh0 = (const float*)d_in[11];
  const float* dbih0 = (const float*)d_in[12];
  const float* dbhh0 = (const float*)d_in[13];
  const float* dWih1 = (const float*)d_in[14];
  const float* dWhh1 = (const float*)d_in[15];
  const float* dbih1 = (const float*)d_in[16];
  const float* dbhh1 = (const float*)d_in[17];
  const float* fcW   = (const float*)d_in[18];
  const float* fcb   = (const float*)d_in[19];
  float* dout = (float*)d_out;

  char* wsb = (char*)d_ws;
  float* af   = (float*)(wsb + 0);          // 128x512 f32 (a / d0 state, RMW)
  float* cf   = (float*)(wsb + 262144);     // 128x512 f32 (c / d1 state, RMW)
  u16* ABF0   = (u16*)(wsb + 524288);       // split states 128x1024 u16 each
  u16* ABF1   = (u16*)(wsb + 786432);
  u16* CBF0   = (u16*)(wsb + 1048576);
  u16* CBF1   = (u16*)(wsb + 1310720);
  int* tok    = (int*)(wsb + 1572864);
  float* simt = (float*)(wsb + 1573376);    // [S][B] f32, 256 KB
  u16* WeHH0  = (u16*)(wsb + 1835520);      // split weights, 3 MB each
  u16* WeIH1  = (u16*)(wsb + 4981248);
  u16* WeHH1  = (u16*)(wsb + 8126976);
  u16* WdIH0  = (u16*)(wsb + 11272704);
  u16* WdHH0  = (u16*)(wsb + 14418432);
  u16* WdIH1  = (u16*)(wsb + 17564160);
  u16* WdHH1  = (u16*)(wsb + 20709888);
  u16* EMBs   = (u16*)(wsb + 23855616);     // 30x1024 u16
  u16* oe     = (u16*)(wsb + 23917056);     // out_enc bf16 [B][S][H], 64 MiB

  initk<<<512, 256, 0, stream>>>(af, cf, ABF0, ABF1, CBF0, CBF1, tok);

  splitall<<<21564, 256, 0, stream>>>(eWhh0, WeHH0, eWih1, WeIH1, eWhh1, WeHH1,
                                      dWih0, WdIH0, dWhh0, WdHH0, dWih1, WdIH1,
                                      dWhh1, WdHH1, emb, EMBs);

  enc_persist<<<96, 256, 0, stream>>>(x, eWih0, WeHH0, ebih0, ebhh0,
                                      WeIH1, WeHH1, ebih1, ebhh1,
                                      ABF0, ABF1, af, CBF0, CBF1, cf, oe);

  // a_511 split in ABF0 (written p=511); c_511 split in CBF1 (written p=512)
  dec_persist<<<256, 256, 0, stream>>>(EMBs, tok, WdIH0, WdHH0, dbih0, dbhh0,
                                       WdIH1, WdHH1, dbih1, dbhh1,
                                       af, cf, ABF0, ABF1, CBF1, CBF0,
                                       oe, simt, fcW, fcb, dout);

  finalize<<<256, 256, 0, stream>>>(af, cf, dout + (size_t)BB * TT * VV);
}

// Round 8
// 25752.164 us; speedup vs baseline: 1.4125x; 1.3142x over previous
//
#include <hip/hip_runtime.h>
#include <math.h>

typedef short  s16x8 __attribute__((ext_vector_type(8)));
typedef float  f32x4 __attribute__((ext_vector_type(4)));
typedef unsigned short u16;
typedef unsigned long long u64;

#define MFMA16(a, b, c) __builtin_amdgcn_mfma_f32_16x16x32_bf16((a), (b), (c), 0, 0, 0)

#define BB 128
#define SS 512
#define HH 512
#define VV 30
#define TT 64

#define SC_SYS  __HIP_MEMORY_SCOPE_SYSTEM

__device__ __forceinline__ float b2f(u16 v) {
  union { unsigned int u; float f; } c; c.u = ((unsigned int)v) << 16; return c.f;
}
__device__ __forceinline__ u16 f2b(float f) {
  union { float f; unsigned int u; } c; c.f = f;
  unsigned int r = (c.u + 0x7FFFu + ((c.u >> 16) & 1u)) >> 16;
  return (u16)r;
}
__device__ __forceinline__ float sigm(float x) { return 1.f / (1.f + expf(-x)); }
__device__ __forceinline__ s16x8 ldf(const u16* p) { return *(const s16x8*)p; }

// ---- coherent (MALL-level) helpers for cross-block data ----
__device__ __forceinline__ u64  ld64c(const u64* p)      { return __hip_atomic_load(p, __ATOMIC_RELAXED, SC_SYS); }
__device__ __forceinline__ void st16c(u16* p, u16 v)     { __hip_atomic_store(p, v, __ATOMIC_RELAXED, SC_SYS); }
__device__ __forceinline__ void stf32c(float* p, float v){ __hip_atomic_store(p, v, __ATOMIC_RELAXED, SC_SYS); }
__device__ __forceinline__ float ldf32c(const float* p)  { return __hip_atomic_load(p, __ATOMIC_RELAXED, SC_SYS); }
__device__ __forceinline__ void sti32c(int* p, int v)    { __hip_atomic_store(p, v, __ATOMIC_RELAXED, SC_SYS); }
__device__ __forceinline__ int  ldi32c(const int* p)     { return __hip_atomic_load(p, __ATOMIC_RELAXED, SC_SYS); }

// ---------------------------------------------------------------------
// Dataflow synchronization (verified R6/R7): per-producer-group monotone
// system-scope counters. waitp(): relaxed poll + timeout.
// ---------------------------------------------------------------------
__device__ unsigned int g_cnt[8];
__device__ float g_smx[SS], g_ssum[SS];

#define C_L0 0
#define C_L1 1
#define C_G0 2
#define C_G1 3
#define C_SIM 4
#define C_SMX 5
#define C_ATT 6

__device__ __forceinline__ void waitp(int idx, int target) {
  if (target <= 0) return;
  unsigned long long t0 = __builtin_amdgcn_s_memrealtime();
  while ((int)__hip_atomic_load(&g_cnt[idx], __ATOMIC_RELAXED, SC_SYS) < target) {
    __builtin_amdgcn_s_sleep(1);
    if (__builtin_amdgcn_s_memrealtime() - t0 > (1ull << 21)) break;
  }
}
__device__ __forceinline__ void waitc2(int i1, int t1, int i2, int t2) {
  if (threadIdx.x == 0) { waitp(i1, t1); waitp(i2, t2); }
  __syncthreads();
}
__device__ __forceinline__ void waitc3(int i1, int t1, int i2, int t2, int i3, int t3) {
  if (threadIdx.x == 0) { waitp(i1, t1); waitp(i2, t2); waitp(i3, t3); }
  __syncthreads();
}
__device__ __forceinline__ void waitc4(int i1, int t1, int i2, int t2, int i3, int t3, int i4, int t4) {
  if (threadIdx.x == 0) { waitp(i1, t1); waitp(i2, t2); waitp(i3, t3); waitp(i4, t4); }
  __syncthreads();
}
__device__ __forceinline__ void arrive(int idx) {
  __syncthreads();
  if (threadIdx.x == 0) {
    asm volatile("s_waitcnt vmcnt(0) lgkmcnt(0)" ::: "memory");
    __hip_atomic_fetch_add(&g_cnt[idx], 1u, __ATOMIC_RELAXED, SC_SYS);
  }
}

// ---------------------------------------------------------------------
// State buffers live in chunked SBUF layout: u16 SBUF[32][128][32].
// Chunk (g,m) = one 64B line: u16 idx 0..15 = hi of cols [16g,16g+16),
// idx 16..31 = lo. Producer block g writes each chunk as 2x32B runs
// (full-line ownership -> write-combining). Consumer staging is LINEAR:
// u64 word index of (g,m,w) = (g*128+m)*8 + w, so per unroll-j the wave
// loads "base_j + tid" -> 2KB contiguous per instruction (R7 bug: 8B per
// 64B line per lane -> ~40us/phase of serialized MALL round trips).
//
// LDS per row: 256 u16 = 32 slots of 16B; slot s at (s ^ (row&15)).
// Verified 2-way max on both ds_write (8 lanes/chunk, rows distinct
// mod 16) and ds_read_b128 (16 rows x distinct lrow).
// ---------------------------------------------------------------------
__device__ __forceinline__ s16x8 ldl(const u16* SM, int row, int slot) {
  return *(const s16x8*)&SM[(row << 8) + ((slot ^ (row & 15)) << 3)];
}

// Stage 64 rows (mbase..mbase+63) of one SBUF source for K-chunk kc into
// LDS rows 0..63 of SMb. 16 coalesced u64 loads + 16 ds_write_b64.
__device__ __forceinline__ void stage64(u16* SMb, const u16* SRC, int mbase, int kc) {
  const int t = threadIdx.x;
  const u64* base = (const u64*)SRC;
  u64 v[16];
#pragma unroll
  for (int j = 0; j < 16; ++j) {
    const int g = kc * 8 + (j >> 1);
    const int half = j & 1;
    v[j] = ld64c(base + (size_t)(g * 128 + mbase + half * 32) * 8 + t);
  }
#pragma unroll
  for (int j = 0; j < 16; ++j) {
    const int gl = j >> 1, half = j & 1;
    const int row = half * 32 + (t >> 3);
    const int w = t & 7;
    const int s = ((w & 4) << 2) + 2 * gl + ((w >> 1) & 1);
    *(u64*)&SMb[(row << 8) + ((s ^ (row & 15)) << 3) + ((w & 1) << 2)] = v[j];
  }
}

// Stage all 128 rows (enc-l0) for K-chunk kc. 32 coalesced u64 loads.
__device__ __forceinline__ void stage128(u16* SM, const u16* SRC, int kc) {
  const int t = threadIdx.x;
  const u64* base = (const u64*)SRC;
  u64 v[32];
#pragma unroll
  for (int j = 0; j < 32; ++j) {
    const int g = kc * 8 + (j >> 2);
    const int q = j & 3;
    v[j] = ld64c(base + (size_t)(g * 128 + q * 32) * 8 + t);
  }
#pragma unroll
  for (int j = 0; j < 32; ++j) {
    const int gl = j >> 2, q = j & 3;
    const int row = q * 32 + (t >> 3);
    const int w = t & 7;
    const int s = ((w & 4) << 2) + 2 * gl + ((w >> 1) & 1);
    *(u64*)&SM[(row << 8) + ((s ^ (row & 15)) << 3) + ((w & 1) << 2)] = v[j];
  }
}

// Split-f32 format per logical row of K=512: hi = bf16(v), lo = bf16(v-hi).
// GEMM does hi*hi + hi*lo + lo*hi (Markidis).

// =====================================================================
// Dual-input GRU cell (enc-l1 / decoder): 64 block-roles x 256 thr.
// GATHER: a1 = EMBs[gather[m]] (old row-major layout, plain cached);
// otherwise a1 staged from SBUF. a2 always staged. Weights plain cached.
// =====================================================================
template <bool GATHER, bool COH_H>
__device__ __forceinline__ void gru_dual_staged(
    int bx, u16* SM,
    const u16* __restrict__ A1s, const int* __restrict__ gather,
    const u16* __restrict__ A2s,
    const u16* __restrict__ Wihs, const u16* __restrict__ Whhs,
    const float* __restrict__ bih, const float* __restrict__ bhh,
    float* __restrict__ hf, u16* __restrict__ hs_new,
    u16* __restrict__ oe, size_t oe_mstride)
{
  const int tid  = threadIdx.x;
  const int wave = tid >> 6, lane = tid & 63;
  const int lrow = lane & 15, lq = lane >> 4;
  const int gidx = bx >> 1;             // 16-col group
  const int j0 = gidx * 16;
  const int mbase = (bx & 1) * 64;
  const int lr = wave * 16 + lrow;      // local row 0..63
  const int m0 = mbase + wave * 16;

  const u16* a1p = nullptr;
  if (GATHER)
    a1p = A1s + (size_t)ldi32c(&gather[m0 + lrow]) * 1024 + lq * 8;

  const u16* bp[6];
#pragma unroll
  for (int t = 0; t < 6; ++t) {
    int g = (t < 3) ? t : t - 3;
    const u16* W = (t < 3) ? Wihs : Whhs;
    bp[t] = W + (size_t)(g * HH + j0 + lrow) * 1024 + lq * 8;
  }

  f32x4 acc[6];
#pragma unroll
  for (int t = 0; t < 6; ++t) acc[t] = (f32x4){0.f, 0.f, 0.f, 0.f};

  for (int kc = 0; kc < 4; ++kc) {
    if (!GATHER) stage64(SM, A1s, mbase, kc);
    stage64(SM + 64 * 256, A2s, mbase, kc);
    __syncthreads();
#pragma unroll
    for (int ki = 0; ki < 4; ++ki) {
      const int sl = ki * 4 + lq;
      s16x8 a1h, a1l;
      if (GATHER) { a1h = ldf(a1p); a1l = ldf(a1p + 512); a1p += 32; }
      else        { a1h = ldl(SM, lr, sl); a1l = ldl(SM, lr, 16 + sl); }
      s16x8 a2h = ldl(SM, 64 + lr, sl), a2l = ldl(SM, 64 + lr, 16 + sl);
#pragma unroll
      for (int t = 0; t < 6; ++t) {
        s16x8 bh = ldf(bp[t]), bl = ldf(bp[t] + 512); bp[t] += 32;
        s16x8 ah = (t < 3) ? a1h : a2h;
        s16x8 al = (t < 3) ? a1l : a2l;
        acc[t] = MFMA16(ah, bh, acc[t]);
        acc[t] = MFMA16(ah, bl, acc[t]);
        acc[t] = MFMA16(al, bh, acc[t]);
      }
    }
    __syncthreads();
  }

  const int c = j0 + lrow;
  const float bir = bih[c], biz = bih[HH + c], bin = bih[2 * HH + c];
  const float bhr = bhh[c], bhz = bhh[HH + c], bhn = bhh[2 * HH + c];
#pragma unroll
  for (int r = 0; r < 4; ++r) {
    int m = mbase + wave * 16 + lq * 4 + r;
    float ir = acc[0][r] + bir, iz = acc[1][r] + biz, inn = acc[2][r] + bin;
    float hr = acc[3][r] + bhr, hz = acc[4][r] + bhz, hn = acc[5][r] + bhn;
    float rr = sigm(ir + hr);
    float zz = sigm(iz + hz);
    float nn = tanhf(inn + rr * hn);
    float hp = COH_H ? ldf32c(&hf[(size_t)m * HH + c]) : hf[(size_t)m * HH + c];
    float hv = (1.f - zz) * nn + zz * hp;
    if (COH_H) stf32c(&hf[(size_t)m * HH + c], hv);
    else       hf[(size_t)m * HH + c] = hv;
    u16 hi = f2b(hv);
    size_t cb = (size_t)(gidx * 128 + m) * 32 + lrow;   // SBUF chunk slot
    st16c(&hs_new[cb], hi);
    st16c(&hs_new[cb + 16], f2b(hv - b2f(hi)));
    if (oe) oe[(size_t)m * oe_mstride + c] = hi;   // read only by next kernel
  }
}

// Encoder layer-0: gh via MFMA (staged split A, cached split Whh0); gi inline f32.
__device__ __forceinline__ void gru_l0_staged(
    int bx, int p, u16* SM,
    const float* __restrict__ x, const float* __restrict__ Wih0,
    const u16* __restrict__ Whh0s,
    const float* __restrict__ bih0, const float* __restrict__ bhh0,
    const u16* __restrict__ As,
    float* __restrict__ af, u16* __restrict__ as_new)
{
  const int tid  = threadIdx.x;
  const int wave = tid >> 6, lane = tid & 63;
  const int lrow = lane & 15, lq = lane >> 4;
  const int j0 = bx * 16;
  const int mw = wave * 32;
  const int r0 = mw + lrow, r1 = mw + 16 + lrow;

  const u16* bp[3];
#pragma unroll
  for (int t = 0; t < 3; ++t)
    bp[t] = Whh0s + (size_t)(t * HH + j0 + lrow) * 1024 + lq * 8;

  f32x4 acc[2][3];
#pragma unroll
  for (int i = 0; i < 2; ++i)
#pragma unroll
    for (int t = 0; t < 3; ++t) acc[i][t] = (f32x4){0.f, 0.f, 0.f, 0.f};

  for (int kc = 0; kc < 4; ++kc) {
    stage128(SM, As, kc);
    __syncthreads();
#pragma unroll
    for (int ki = 0; ki < 4; ++ki) {
      const int sl = ki * 4 + lq;
      s16x8 a0h = ldl(SM, r0, sl), a0l = ldl(SM, r0, 16 + sl);
      s16x8 a1h = ldl(SM, r1, sl), a1l = ldl(SM, r1, 16 + sl);
#pragma unroll
      for (int t = 0; t < 3; ++t) {
        s16x8 bh = ldf(bp[t]), bl = ldf(bp[t] + 512); bp[t] += 32;
        acc[0][t] = MFMA16(a0h, bh, acc[0][t]);
        acc[0][t] = MFMA16(a0h, bl, acc[0][t]);
        acc[0][t] = MFMA16(a0l, bh, acc[0][t]);
        acc[1][t] = MFMA16(a1h, bh, acc[1][t]);
        acc[1][t] = MFMA16(a1h, bl, acc[1][t]);
        acc[1][t] = MFMA16(a1l, bh, acc[1][t]);
      }
    }
    __syncthreads();
  }

  const int c = j0 + lrow;
  const float bir = bih0[c], biz = bih0[HH + c], bin = bih0[2 * HH + c];
  const float bhr = bhh0[c], bhz = bhh0[HH + c], bhn = bhh0[2 * HH + c];
  const float wr0 = Wih0[(size_t)c * 2],            wr1 = Wih0[(size_t)c * 2 + 1];
  const float wz0 = Wih0[(size_t)(HH + c) * 2],     wz1 = Wih0[(size_t)(HH + c) * 2 + 1];
  const float wn0 = Wih0[(size_t)(2 * HH + c) * 2], wn1 = Wih0[(size_t)(2 * HH + c) * 2 + 1];
#pragma unroll
  for (int tm = 0; tm < 2; ++tm) {
#pragma unroll
    for (int r = 0; r < 4; ++r) {
      int m = mw + tm * 16 + lq * 4 + r;
      float x0 = x[((size_t)m * SS + p) * 2];
      float x1 = x[((size_t)m * SS + p) * 2 + 1];
      float ir  = bir + x0 * wr0 + x1 * wr1;
      float iz  = biz + x0 * wz0 + x1 * wz1;
      float inn = bin + x0 * wn0 + x1 * wn1;
      float hr = acc[tm][0][r] + bhr, hz = acc[tm][1][r] + bhz, hn = acc[tm][2][r] + bhn;
      float rr = sigm(ir + hr);
      float zz = sigm(iz + hz);
      float nn = tanhf(inn + rr * hn);
      float hp = af[(size_t)m * HH + c];      // same-thread RMW
      float hv = (1.f - zz) * nn + zz * hp;
      af[(size_t)m * HH + c] = hv;
      u16 hi = f2b(hv);
      size_t cb = (size_t)(bx * 128 + m) * 32 + lrow;   // SBUF chunk slot
      st16c(&as_new[cb], hi);
      st16c(&as_new[cb + 16], f2b(hv - b2f(hi)));
    }
  }
}

// sim[s][b] = dot(out_enc[b,s,:], n1[b,:]). b = bx>>1, s-half = bx&1.
__device__ __forceinline__ void sim_block(
    int bx, const float* __restrict__ n1f, const u16* __restrict__ oe,
    float* __restrict__ simt)
{
  const int b = bx >> 1, sc = bx & 1;
  const int wave = threadIdx.x >> 6, lane = threadIdx.x & 63;
  float xr[8];
  const u64* xp = (const u64*)(n1f + (size_t)b * HH + lane * 8);
#pragma unroll
  for (int j = 0; j < 4; ++j) {
    union { u64 q; float f[2]; } u; u.q = ld64c(xp + j);
    xr[2 * j] = u.f[0]; xr[2 * j + 1] = u.f[1];
  }
  int s0 = sc * 256 + wave * 64;
  for (int i = 0; i < 64; ++i) {
    int s = s0 + i;
    s16x8 ov = *(const s16x8*)(oe + ((size_t)b * SS + s) * HH + lane * 8);
    float acc = 0.f;
#pragma unroll
    for (int j = 0; j < 8; ++j) acc += xr[j] * b2f((u16)ov[j]);
    for (int off = 32; off; off >>= 1) acc += __shfl_down(acc, off);
    if (lane == 0) stf32c(&simt[(size_t)s * BB + b], acc);
  }
}

// Per-s softmax stats over batch dim (reference dim=0 quirk), computed ONCE.
__device__ __forceinline__ void smax_block(int bx, const float* __restrict__ simt)
{
  const int wave = threadIdx.x >> 6, lane = threadIdx.x & 63;
  const int s = bx * 4 + wave;
  union { u64 q; float f[2]; } u;
  u.q = ld64c((const u64*)&simt[(size_t)s * BB + lane * 2]);
  float mx = fmaxf(u.f[0], u.f[1]);
  for (int off = 32; off; off >>= 1) mx = fmaxf(mx, __shfl_xor(mx, off));
  float e = expf(u.f[0] - mx) + expf(u.f[1] - mx);
  for (int off = 32; off; off >>= 1) e += __shfl_xor(e, off);
  if (lane == 0) { stf32c(&g_smx[s], mx); stf32c(&g_ssum[s], e); }
}

// attention -> logits -> argmax feedback. One block per batch element.
__device__ __forceinline__ void attn_block(
    int b, int tstep, const float* __restrict__ simt, const float* __restrict__ n1f,
    const u16* __restrict__ oe, const float* __restrict__ fcW,
    const float* __restrict__ fcb, float* __restrict__ dout,
    int* __restrict__ tok)
{
  __shared__ float wsm[SS];
  __shared__ float xv[2 * HH];
  __shared__ float lg[32];
  const int t = threadIdx.x;

  for (int s = t; s < SS; s += 256) {
    float sv = ldf32c(&simt[(size_t)s * BB + b]);
    float mx = ldf32c(&g_smx[s]);
    float sm = ldf32c(&g_ssum[s]);
    wsm[s] = expf(sv - mx) / sm;
  }
  xv[t]       = ldf32c(&n1f[(size_t)b * HH + t]);
  xv[t + 256] = ldf32c(&n1f[(size_t)b * HH + t + 256]);
  __syncthreads();

  {
    float a0 = 0.f, a1 = 0.f;
    const u16* base = oe + (size_t)b * SS * HH;   // read-only: cached
    for (int s = 0; s < SS; ++s) {
      float w = wsm[s];
      a0 += w * b2f(base[(size_t)s * HH + t]);
      a1 += w * b2f(base[(size_t)s * HH + t + 256]);
    }
    xv[HH + t]       = a0;
    xv[HH + t + 256] = a1;
  }
  __syncthreads();

  int wave = t >> 6, lane = t & 63;
  for (int v = wave; v < VV; v += 4) {
    const float* wr = fcW + (size_t)v * (2 * HH);
    float acc = 0.f;
#pragma unroll
    for (int i = 0; i < 16; ++i) acc += xv[i * 64 + lane] * wr[i * 64 + lane];
    for (int off = 32; off; off >>= 1) acc += __shfl_down(acc, off);
    if (lane == 0) {
      float lv = acc + fcb[v];
      lg[v] = lv;
      dout[(size_t)b * (TT * VV) + (size_t)tstep * VV + v] = lv;  // host-read
    }
  }
  __syncthreads();

  if (t == 0) {
    float best = lg[0]; int bi = 0;
    for (int v = 1; v < VV; ++v) if (lg[v] > best) { best = lg[v]; bi = v; }
    sti32c(&tok[b], bi);
  }
}

// =====================================================================
// Persistent encoder: 96 blocks, 513 phases, dataflow counters (R7).
// =====================================================================
__global__ __launch_bounds__(256) void enc_persist(
    const float* __restrict__ x, const float* __restrict__ Wih0,
    const u16* __restrict__ Whh0s,
    const float* __restrict__ bih0, const float* __restrict__ bhh0,
    const u16* __restrict__ Wih1s, const u16* __restrict__ Whh1s,
    const float* __restrict__ bih1, const float* __restrict__ bhh1,
    u16* ABF0, u16* ABF1, float* af,
    u16* CBF0, u16* CBF1, float* cf,
    u16* out_enc)
{
  __shared__ u16 SM[32768];
  const int bx = blockIdx.x;
  const u16* pa = ABF0; u16* pa_n = ABF1;
  const u16* pc = CBF0; u16* pc_n = CBF1;
  for (int p = 0; p <= SS; ++p) {
    waitc2(C_L0, 32 * p, C_L1, 64 * (p - 1));
    if (bx < 32) {
      if (p < SS) {
        gru_l0_staged(bx, p, SM, x, Wih0, Whh0s, bih0, bhh0, pa, af, pa_n);
        arrive(C_L0);
      }
    } else {
      if (p > 0) {
        u16* oe = out_enc + (size_t)(p - 1) * HH;
        gru_dual_staged<false, false>(bx - 32, SM, pa, nullptr, pc,
                                      Wih1s, Whh1s, bih1, bhh1,
                                      cf, pc_n, oe, (size_t)SS * HH);
        arrive(C_L1);
      }
    }
    const u16* tp;
    tp = pa; pa = pa_n; pa_n = (u16*)tp;
    tp = pc; pc = pc_n; pc_n = (u16*)tp;
  }
}

// =====================================================================
// Persistent decoder: 256 blocks, 64 steps x 5 dataflow phases (R7).
// =====================================================================
__global__ __launch_bounds__(256) void dec_persist(
    const u16* __restrict__ EMBs, int* tok,
    const u16* __restrict__ WdIH0, const u16* __restrict__ WdHH0,
    const float* __restrict__ dbih0, const float* __restrict__ dbhh0,
    const u16* __restrict__ WdIH1, const u16* __restrict__ WdHH1,
    const float* __restrict__ dbih1, const float* __restrict__ dbhh1,
    float* af, float* cf,
    u16* D0A, u16* D0B, u16* D1A, u16* D1B,
    const u16* __restrict__ oe, float* simt,
    const float* __restrict__ fcW, const float* __restrict__ fcb,
    float* dout)
{
  __shared__ u16 SM[32768];
  const int bx = blockIdx.x;
  const u16* d0c = D0A; u16* d0n = D0B;
  const u16* d1c = D1A; u16* d1n = D1B;
  for (int t = 0; t < TT; ++t) {
    if (bx < 64) {
      waitc3(C_G0, 64 * t, C_ATT, 128 * t, C_G1, 64 * (t - 1));
      gru_dual_staged<true, false>(bx, SM, EMBs, tok, d0c,
                                   WdIH0, WdHH0, dbih0, dbhh0, af, d0n,
                                   nullptr, 0);
      arrive(C_G0);
    }
    { const u16* tp = d0c; d0c = d0n; d0n = (u16*)tp; }

    if (bx < 64) {
      waitc4(C_G0, 64 * (t + 1), C_G1, 64 * t, C_SIM, 256 * t, C_ATT, 128 * t);
      gru_dual_staged<false, true>(bx, SM, d0c, nullptr, d1c,
                                   WdIH1, WdHH1, dbih1, dbhh1, cf, d1n,
                                   nullptr, 0);
      arrive(C_G1);
    }
    { const u16* tp = d1c; d1c = d1n; d1n = (u16*)tp; }

    waitc3(C_G1, 64 * (t + 1), C_SMX, 128 * t, C_ATT, 128 * t);
    sim_block(bx, cf, oe, simt);
    arrive(C_SIM);

    if (bx < 128) {
      waitc2(C_SIM, 256 * (t + 1), C_ATT, 128 * t);
      smax_block(bx, simt);
      arrive(C_SMX);
    }

    if (bx < BB) {
      waitc4(C_SMX, 128 * (t + 1), C_SIM, 256 * (t + 1),
             C_G1, 64 * (t + 1), C_G0, 64 * (t + 1));
      attn_block(bx, t, simt, cf, oe, fcW, fcb, dout, tok);
      arrive(C_ATT);
    }
  }
}

// Split weights (old row-major layout: row r -> [hi x512 | lo x512]).
__global__ __launch_bounds__(256) void splitall(
    const float* __restrict__ s0, u16* d0, const float* __restrict__ s1, u16* d1,
    const float* __restrict__ s2, u16* d2, const float* __restrict__ s3, u16* d3,
    const float* __restrict__ s4, u16* d4, const float* __restrict__ s5, u16* d5,
    const float* __restrict__ s6, u16* d6, const float* __restrict__ s7, u16* d7)
{
  const int WN = 3 * HH * HH;  // 786432
  int i = blockIdx.x * 256 + threadIdx.x;
  const float* s; u16* d; int j;
  if      (i < 1 * WN) { s = s0; d = d0; j = i; }
  else if (i < 2 * WN) { s = s1; d = d1; j = i - 1 * WN; }
  else if (i < 3 * WN) { s = s2; d = d2; j = i - 2 * WN; }
  else if (i < 4 * WN) { s = s3; d = d3; j = i - 3 * WN; }
  else if (i < 5 * WN) { s = s4; d = d4; j = i - 4 * WN; }
  else if (i < 6 * WN) { s = s5; d = d5; j = i - 5 * WN; }
  else if (i < 7 * WN) { s = s6; d = d6; j = i - 6 * WN; }
  else { j = i - 7 * WN; if (j >= VV * HH) return; s = s7; d = d7; }
  int r = j >> 9, k = j & 511;
  float v = s[j];
  u16 hi = f2b(v);
  d[(size_t)r * 1024 + k]       = hi;
  d[(size_t)r * 1024 + 512 + k] = f2b(v - b2f(hi));
}

__global__ __launch_bounds__(256) void initk(
    float* af, float* cf, u16* b0, u16* b1, u16* b2, u16* b3, int* tok)
{
  int i = blockIdx.x * 256 + threadIdx.x;   // 131072 threads
  b0[i] = 0; b1[i] = 0; b2[i] = 0; b3[i] = 0;
  if (i < BB * HH) { af[i] = 0.f; cf[i] = 0.f; }
  if (i < BB) tok[i] = 0;
  if (i < 8) g_cnt[i] = 0;
}

__global__ __launch_bounds__(256) void finalize(
    const float* __restrict__ d0, const float* __restrict__ d1,
    float* __restrict__ oh)
{
  int i = blockIdx.x * 256 + threadIdx.x;
  oh[i]           = d0[i];
  oh[BB * HH + i] = d1[i];
}

extern "C" void kernel_launch(void* const* d_in, const int* in_sizes, int n_in,
                              void* d_out, int out_size, void* d_ws, size_t ws_size,
                              hipStream_t stream) {
  const float* x     = (const float*)d_in[0];
  const float* emb   = (const float*)d_in[1];
  const float* eWih0 = (const float*)d_in[2];
  const float* eWhh0 = (const float*)d_in[3];
  const float* ebih0 = (const float*)d_in[4];
  const float* ebhh0 = (const float*)d_in[5];
  const float* eWih1 = (const float*)d_in[6];
  const float* eWhh1 = (const float*)d_in[7];
  const float* ebih1 = (const float*)d_in[8];
  const float* ebhh1 = (const float*)d_in[9];
  const float* dWih0 = (const float*)d_in[10];
  const float* dWhh0 = (const float*)d_in[11];
  const float* dbih0 = (const float*)d_in[12];
  const float* dbhh0 = (const float*)d_in[13];
  const float* dWih1 = (const float*)d_in[14];
  const float* dWhh1 = (const float*)d_in[15];
  const float* dbih1 = (const float*)d_in[16];
  const float* dbhh1 = (const float*)d_in[17];
  const float* fcW   = (const float*)d_in[18];
  const float* fcb   = (const float*)d_in[19];
  float* dout = (float*)d_out;

  char* wsb = (char*)d_ws;
  float* af   = (float*)(wsb + 0);          // 128x512 f32 (a / d0 state, RMW)
  float* cf   = (float*)(wsb + 262144);     // 128x512 f32 (c / d1 state, RMW)
  u16* ABF0   = (u16*)(wsb + 524288);       // SBUF-layout states, 256KB each
  u16* ABF1   = (u16*)(wsb + 786432);
  u16* CBF0   = (u16*)(wsb + 1048576);
  u16* CBF1   = (u16*)(wsb + 1310720);
  int* tok    = (int*)(wsb + 1572864);
  float* simt = (float*)(wsb + 1573376);    // [S][B] f32, 256 KB
  u16* WeHH0  = (u16*)(wsb + 1835520);      // split weights, 3 MB each
  u16* WeIH1  = (u16*)(wsb + 4981248);
  u16* WeHH1  = (u16*)(wsb + 8126976);
  u16* WdIH0  = (u16*)(wsb + 11272704);
  u16* WdHH0  = (u16*)(wsb + 14418432);
  u16* WdIH1  = (u16*)(wsb + 17564160);
  u16* WdHH1  = (u16*)(wsb + 20709888);
  u16* EMBs   = (u16*)(wsb + 23855616);     // 30x1024 u16, old layout
  u16* oe     = (u16*)(wsb + 23917056);     // out_enc bf16 [B][S][H], 64 MiB

  initk<<<512, 256, 0, stream>>>(af, cf, ABF0, ABF1, CBF0, CBF1, tok);

  splitall<<<21564, 256, 0, stream>>>(eWhh0, WeHH0, eWih1, WeIH1, eWhh1, WeHH1,
                                      dWih0, WdIH0, dWhh0, WdHH0, dWih1, WdIH1,
                                      dWhh1, WdHH1, emb, EMBs);

  enc_persist<<<96, 256, 0, stream>>>(x, eWih0, WeHH0, ebih0, ebhh0,
                                      WeIH1, WeHH1, ebih1, ebhh1,
                                      ABF0, ABF1, af, CBF0, CBF1, cf, oe);

  // a_511 SBUF in ABF0 (written p=511); c_511 SBUF in CBF1 (written p=512)
  dec_persist<<<256, 256, 0, stream>>>(EMBs, tok, WdIH0, WdHH0, dbih0, dbhh0,
                                       WdIH1, WdHH1, dbih1, dbhh1,
                                       af, cf, ABF0, ABF1, CBF1, CBF0,
                                       oe, simt, fcW, fcb, dout);

  finalize<<<256, 256, 0, stream>>>(af, cf, dout + (size_t)BB * TT * VV);
}